// Round 1
// baseline (7992.751 us; speedup 1.0000x reference)
//
#include <hip/hip_runtime.h>
#include <math.h>

#define SPX 1024
#define HW 16384

// ---------------- superpixel mean pooling: out[s,c] = mean_{j} img[c, s+1024j] ----------------
__global__ __launch_bounds__(256) void pool_ct_k(const float* __restrict__ img, float* __restrict__ out, int C)
{
    int tid = blockIdx.x * 256 + threadIdx.x;
    if (tid >= SPX * C) return;
    int c = tid >> 10;
    int s = tid & 1023;
    const float* p = img + (size_t)c * HW + s;
    float acc = 0.f;
#pragma unroll
    for (int j = 0; j < 16; ++j) acc += p[j * SPX];
    out[(size_t)s * C + c] = acc * (1.f / 16.f);
}

// ---------------- direct 3x3 SAME conv, 128x128, Cout multiple of 16 ----------------
// grid: (64 tiles, Cout/16); block 256. Tile: 16x16 pixels x 16 co. Thread: 2x2 px x 4 co.
__global__ __launch_bounds__(256) void conv3x3_k(const float* __restrict__ in, const float* __restrict__ Wt,
                                                 const float* __restrict__ bias, float* __restrict__ out, int Cin)
{
    __shared__ float s_in[18 * 18];
    __shared__ __align__(16) float s_w[9][16];
    int tid = threadIdx.x;
    int gx0 = (blockIdx.x & 7) * 16;
    int gy0 = (blockIdx.x >> 3) * 16;
    int cog = blockIdx.y * 16;
    int px = tid & 7, py = (tid >> 3) & 7, cs = tid >> 6;
    float acc[2][2][4];
#pragma unroll
    for (int r = 0; r < 2; ++r)
#pragma unroll
        for (int c = 0; c < 2; ++c)
#pragma unroll
            for (int w = 0; w < 4; ++w) acc[r][c][w] = 0.f;

    for (int ci = 0; ci < Cin; ++ci) {
        int idx = tid;
#pragma unroll
        for (int rep = 0; rep < 2; ++rep) {
            if (idx < 324) {
                int iy = gy0 - 1 + idx / 18;
                int ix = gx0 - 1 + idx % 18;
                float v = 0.f;
                if (iy >= 0 && iy < 128 && ix >= 0 && ix < 128)
                    v = in[(size_t)ci * HW + iy * 128 + ix];
                s_in[idx] = v;
            }
            idx += 256;
        }
        if (tid < 144) {
            int col = tid & 15, k = tid >> 4;
            s_w[k][col] = Wt[((size_t)(cog + col) * Cin + ci) * 9 + k];
        }
        __syncthreads();
        float xi[4][4];
#pragma unroll
        for (int r = 0; r < 4; ++r)
#pragma unroll
            for (int c = 0; c < 4; ++c)
                xi[r][c] = s_in[(2 * py + r) * 18 + 2 * px + c];
#pragma unroll
        for (int k = 0; k < 9; ++k) {
            float4 wv = *(const float4*)&s_w[k][cs * 4];
            int dy = k / 3, dx = k % 3;
#pragma unroll
            for (int r = 0; r < 2; ++r)
#pragma unroll
                for (int c = 0; c < 2; ++c) {
                    float iv = xi[r + dy][c + dx];
                    acc[r][c][0] += iv * wv.x;
                    acc[r][c][1] += iv * wv.y;
                    acc[r][c][2] += iv * wv.z;
                    acc[r][c][3] += iv * wv.w;
                }
        }
        __syncthreads();
    }
#pragma unroll
    for (int w = 0; w < 4; ++w) {
        int co = cog + cs * 4 + w;
        float bb = bias[co];
#pragma unroll
        for (int r = 0; r < 2; ++r)
#pragma unroll
            for (int c = 0; c < 2; ++c)
                out[(size_t)co * HW + (size_t)(gy0 + 2 * py + r) * 128 + gx0 + 2 * px + c] = acc[r][c][w] + bb;
    }
}

// ---------------- generic fp32 GEMM: C = act(alpha*A@B(^T) + bias + addm) ----------------
// grid (N/64, M/64, Z); block 256; K % 16 == 0; all leading dims % 4 == 0.
__global__ __launch_bounds__(256) void gemm_f32(const float* __restrict__ A, const float* __restrict__ B,
                                                float* C, int K, int lda, int ldb, int ldc,
                                                long long sA, long long sB, long long sC,
                                                int transB, float alpha, const float* __restrict__ bias,
                                                const float* addm, int ldadd, long long sAdd, int act)
{
    __shared__ __align__(16) float As[16][68];
    __shared__ __align__(16) float Bs[16][68];
    int z = blockIdx.z;
    const float* Ap = A + (long long)z * sA;
    const float* Bp = B + (long long)z * sB;
    float* Cp = C + (long long)z * sC;
    const float* addp = addm ? addm + (long long)z * sAdd : nullptr;
    int bn = blockIdx.x * 64, bm = blockIdx.y * 64;
    int tid = threadIdx.x;
    int tx = tid & 15, ty = tid >> 4;
    float acc[4][4];
#pragma unroll
    for (int r = 0; r < 4; ++r)
#pragma unroll
        for (int c = 0; c < 4; ++c) acc[r][c] = 0.f;

    int mmA = tid >> 2, kqA = (tid & 3) * 4;
    int kkB = tid >> 4, nqB = (tid & 15) * 4;
    int nnB = tid >> 2, kqB = (tid & 3) * 4;

    for (int k0 = 0; k0 < K; k0 += 16) {
        float4 av = *(const float4*)(Ap + (long long)(bm + mmA) * lda + k0 + kqA);
        As[kqA + 0][mmA] = av.x;
        As[kqA + 1][mmA] = av.y;
        As[kqA + 2][mmA] = av.z;
        As[kqA + 3][mmA] = av.w;
        if (!transB) {
            float4 bv = *(const float4*)(Bp + (long long)(k0 + kkB) * ldb + bn + nqB);
            *(float4*)&Bs[kkB][nqB] = bv;
        } else {
            float4 bv = *(const float4*)(Bp + (long long)(bn + nnB) * ldb + k0 + kqB);
            Bs[kqB + 0][nnB] = bv.x;
            Bs[kqB + 1][nnB] = bv.y;
            Bs[kqB + 2][nnB] = bv.z;
            Bs[kqB + 3][nnB] = bv.w;
        }
        __syncthreads();
#pragma unroll
        for (int kk = 0; kk < 16; ++kk) {
            float4 a4 = *(const float4*)&As[kk][ty * 4];
            float4 b4 = *(const float4*)&Bs[kk][tx * 4];
            float ar[4] = {a4.x, a4.y, a4.z, a4.w};
            float br[4] = {b4.x, b4.y, b4.z, b4.w};
#pragma unroll
            for (int r = 0; r < 4; ++r)
#pragma unroll
                for (int c = 0; c < 4; ++c) acc[r][c] += ar[r] * br[c];
        }
        __syncthreads();
    }
#pragma unroll
    for (int r = 0; r < 4; ++r) {
        int row = bm + ty * 4 + r;
        float4 vv;
        float* vp = &vv.x;
#pragma unroll
        for (int c = 0; c < 4; ++c) {
            int col = bn + tx * 4 + c;
            float v = alpha * acc[r][c];
            if (bias) v += bias[col];
            if (addp) v += addp[(long long)row * ldadd + col];
            if (act == 1) v = fmaxf(v, 0.f);
            else if (act == 2) v = 0.5f * v * (1.f + erff(v * 0.70710678118f));
            vp[c] = v;
        }
        *(float4*)(Cp + (long long)row * ldc + bn + tx * 4) = vv;
    }
}

// ---------------- layernorm over 256; optional +pos and residual-stream write ----------------
__global__ __launch_bounds__(256) void ln_k(const float* xin, const float* pos, float* xout,
                                            const float* __restrict__ g, const float* __restrict__ b, float* hout)
{
    int row = blockIdx.x, tid = threadIdx.x;
    __shared__ float red[256];
    size_t o = (size_t)row * 256 + tid;
    float v = xin[o];
    if (pos) v += pos[o];
    if (xout) xout[o] = v;
    red[tid] = v;
    __syncthreads();
    for (int st = 128; st > 0; st >>= 1) {
        if (tid < st) red[tid] += red[tid + st];
        __syncthreads();
    }
    float m = red[0] * (1.f / 256.f);
    __syncthreads();
    float d = v - m;
    red[tid] = d * d;
    __syncthreads();
    for (int st = 128; st > 0; st >>= 1) {
        if (tid < st) red[tid] += red[tid + st];
        __syncthreads();
    }
    float var = red[0] * (1.f / 256.f);
    float rs = rsqrtf(var + 1e-5f);
    hout[o] = d * rs * g[tid] + b[tid];
}

// ---------------- row softmax over 1024 cols ----------------
__global__ __launch_bounds__(256) void softmax_k(float* __restrict__ d)
{
    int row = blockIdx.x, tid = threadIdx.x;
    float* p = d + (long long)row * 1024;
    float v[4];
#pragma unroll
    for (int j = 0; j < 4; ++j) v[j] = p[tid + 256 * j];
    float m = fmaxf(fmaxf(v[0], v[1]), fmaxf(v[2], v[3]));
    __shared__ float red[256];
    red[tid] = m;
    __syncthreads();
    for (int st = 128; st > 0; st >>= 1) {
        if (tid < st) red[tid] = fmaxf(red[tid], red[tid + st]);
        __syncthreads();
    }
    m = red[0];
    __syncthreads();
    float sum = 0.f;
#pragma unroll
    for (int j = 0; j < 4; ++j) { v[j] = expf(v[j] - m); sum += v[j]; }
    red[tid] = sum;
    __syncthreads();
    for (int st = 128; st > 0; st >>= 1) {
        if (tid < st) red[tid] += red[tid + st];
        __syncthreads();
    }
    float inv = 1.f / red[0];
#pragma unroll
    for (int j = 0; j < 4; ++j) p[tid + 256 * j] = v[j] * inv;
}

// ---------------- concat two row blocks + relu: out(1024, ca+cb) ----------------
__global__ __launch_bounds__(256) void concat_relu_k(const float* __restrict__ a, int ca,
                                                     const float* __restrict__ b, int cb, float* __restrict__ out)
{
    int row = blockIdx.x;
    int n = ca + cb;
    for (int col = threadIdx.x; col < n; col += 256) {
        float v = (col < ca) ? a[(size_t)row * ca + col] : b[(size_t)row * cb + (col - ca)];
        out[(size_t)row * n + col] = fmaxf(v, 0.f);
    }
}

__global__ __launch_bounds__(256) void absdiff_k(const float* __restrict__ a, const float* __restrict__ b,
                                                 float* __restrict__ o, int n)
{
    int i = blockIdx.x * 256 + threadIdx.x;
    if (i < n) o[i] = fabsf(a[i] - b[i]);
}

// ---------------- head: logits = h@W2 + b2; softmax over 2 classes ----------------
__global__ __launch_bounds__(256) void head2_k(const float* __restrict__ hh, const float* __restrict__ W2,
                                               const float* __restrict__ b2, float* __restrict__ out)
{
    int s = blockIdx.x * 256 + threadIdx.x;
    if (s >= SPX) return;
    float l0 = b2[0], l1 = b2[1];
    const float* hp = hh + (size_t)s * 128;
    for (int k = 0; k < 128; ++k) {
        float v = hp[k];
        l0 += v * W2[k * 2];
        l1 += v * W2[k * 2 + 1];
    }
    float m = fmaxf(l0, l1);
    float e0 = expf(l0 - m), e1 = expf(l1 - m);
    float inv = 1.f / (e0 + e1);
    out[s * 2] = e0 * inv;
    out[s * 2 + 1] = e1 * inv;
}

extern "C" void kernel_launch(void* const* d_in, const int* in_sizes, int n_in,
                              void* d_out, int out_size, void* d_ws, size_t ws_size,
                              hipStream_t stream)
{
    (void)in_sizes; (void)n_in; (void)out_size; (void)ws_size;
    const float* T1 = (const float*)d_in[0];
    const float* T2 = (const float*)d_in[1];
    // d_in[2] = Q : fixed one-hot (pixel p -> superpixel p & 1023), 16 pixels per superpixel
    const float* Abias = (const float*)d_in[3];
    const float* convW_in = (const float*)d_in[4];
    const float* convB_in = (const float*)d_in[5];
    const float* convW = (const float*)d_in[6];
    const float* convB = (const float*)d_in[7];
    const float* fc0_W = (const float*)d_in[8];
    const float* fc0_b = (const float*)d_in[9];
    const float* fc_W = (const float*)d_in[10];
    const float* fc_b = (const float*)d_in[11];
    const float* pos = (const float*)d_in[12];
    const float* ln1_g = (const float*)d_in[13];
    const float* ln1_b = (const float*)d_in[14];
    const float* qkv_W = (const float*)d_in[15];
    const float* out_W = (const float*)d_in[16];
    const float* out_b = (const float*)d_in[17];
    const float* ln2_g = (const float*)d_in[18];
    const float* ln2_b = (const float*)d_in[19];
    const float* ff_W1 = (const float*)d_in[20];
    const float* ff_b1 = (const float*)d_in[21];
    const float* ff_W2 = (const float*)d_in[22];
    const float* ff_b2 = (const float*)d_in[23];
    const float* head_W1 = (const float*)d_in[24];
    const float* head_b1 = (const float*)d_in[25];
    const float* head_W2 = (const float*)d_in[26];
    const float* head_b2 = (const float*)d_in[27];
    float* outp = (float*)d_out;

    // workspace layout (floats), total ~30.7M floats (~123 MB)
    float* w = (float*)d_ws;
    auto alloc = [&](size_t n) { float* p = w; w += n; return p; };
    float* cbuf[2][2];
    cbuf[0][0] = alloc((size_t)256 * HW);
    cbuf[0][1] = alloc((size_t)256 * HW);
    cbuf[1][0] = alloc((size_t)256 * HW);
    cbuf[1][1] = alloc((size_t)256 * HW);
    float* LS[2];
    LS[0] = alloc((size_t)SPX * 224);
    LS[1] = alloc((size_t)SPX * 224);
    float* pooled = alloc((size_t)SPX * 256);
    float* catr = alloc((size_t)SPX * 512);
    float* xinb = alloc((size_t)SPX * 256);
    float* xb[2];
    xb[0] = alloc((size_t)SPX * 256);
    xb[1] = alloc((size_t)SPX * 256);
    float* hbuf = alloc((size_t)SPX * 256);
    float* qkvb = alloc((size_t)SPX * 1536);
    float* dots = alloc((size_t)8 * SPX * SPX);
    float* obuf = alloc((size_t)SPX * 512);
    float* h2buf = alloc((size_t)SPX * 256);
    float* ffhb = alloc((size_t)SPX * 512);
    float* dabs = alloc((size_t)SPX * 256);
    float* hhb = alloc((size_t)SPX * 128);

    auto gemm = [&](const float* A, const float* B, float* C, int M, int N, int K,
                    int lda, int ldb, int ldc, long long sA, long long sB, long long sC, int Z,
                    int transB, float alpha, const float* bias,
                    const float* addm, int ldadd, long long sAdd, int act) {
        dim3 g((unsigned)(N / 64), (unsigned)(M / 64), (unsigned)Z);
        gemm_f32<<<g, dim3(256), 0, stream>>>(A, B, C, K, lda, ldb, ldc, sA, sB, sC,
                                              transB, alpha, bias, addm, ldadd, sAdd, act);
    };

    auto encoder = [&](int s, int br, float* xin) {
        size_t o1 = (size_t)s * 2 + br;
        const float* posp = pos + o1 * SPX * 256;
        const float* g1 = ln1_g + o1 * 256;
        const float* b1 = ln1_b + o1 * 256;
        const float* qW = qkv_W + o1 * 256 * 1536;
        const float* oW = out_W + o1 * 512 * 256;
        const float* ob = out_b + o1 * 256;
        const float* g2 = ln2_g + o1 * 256;
        const float* b2 = ln2_b + o1 * 256;
        const float* w1 = ff_W1 + o1 * 256 * 512;
        const float* fb1 = ff_b1 + o1 * 512;
        const float* w2 = ff_W2 + o1 * 512 * 256;
        const float* fb2 = ff_b2 + o1 * 256;
        float* x = xb[br];
        // x = xin + pos ; h = LN(x)*g1+b1
        ln_k<<<SPX, 256, 0, stream>>>(xin, posp, x, g1, b1, hbuf);
        // qkv = h @ qW
        gemm(hbuf, qW, qkvb, 1024, 1536, 256, 256, 1536, 1536, 0, 0, 0, 1, 0, 1.f, nullptr, nullptr, 0, 0, 0);
        // dots = q@k^T * 0.125 + A   (z over 8 heads)
        gemm(qkvb, qkvb + 512, dots, 1024, 1024, 64, 1536, 1536, 1024, 64, 64, 1048576, 8,
             1, 0.125f, nullptr, Abias, 1024, 0, 0);
        softmax_k<<<8 * SPX, 256, 0, stream>>>(dots);
        // o = attn @ v
        gemm(dots, qkvb + 1024, obuf, 1024, 64, 1024, 1024, 1536, 512, 1048576, 64, 64, 8,
             0, 1.f, nullptr, nullptr, 0, 0, 0);
        // x = x + o@oW + ob
        gemm(obuf, oW, x, 1024, 256, 512, 512, 256, 256, 0, 0, 0, 1, 0, 1.f, ob, x, 256, 0, 0);
        // h2 = LN(x)*g2+b2
        ln_k<<<SPX, 256, 0, stream>>>(x, nullptr, nullptr, g2, b2, h2buf);
        // ffh = gelu(h2@w1 + fb1)
        gemm(h2buf, w1, ffhb, 1024, 512, 256, 256, 512, 512, 0, 0, 0, 1, 0, 1.f, fb1, nullptr, 0, 0, 2);
        // x = x + ffh@w2 + fb2
        gemm(ffhb, w2, x, 1024, 256, 512, 512, 256, 256, 0, 0, 0, 1, 0, 1.f, fb2, x, 256, 0, 0);
    };

    // LS = pooled raw inputs
    pool_ct_k<<<(SPX * 224) / 256, 256, 0, stream>>>(T1, LS[0], 224);
    pool_ct_k<<<(SPX * 224) / 256, 256, 0, stream>>>(T2, LS[1], 224);
    // input convs (224 -> 256)
    conv3x3_k<<<dim3(64, 16), 256, 0, stream>>>(T1, convW_in, convB_in, cbuf[0][0], 224);
    conv3x3_k<<<dim3(64, 16), 256, 0, stream>>>(T2, convW_in + (size_t)256 * 224 * 9, convB_in + 256, cbuf[1][0], 224);
    int cur[2] = {0, 0};
    // stage 0
    for (int br = 0; br < 2; ++br) {
        pool_ct_k<<<(SPX * 256) / 256, 256, 0, stream>>>(cbuf[br][cur[br]], pooled, 256);
        concat_relu_k<<<SPX, 256, 0, stream>>>(pooled, 256, LS[br], 224, catr);
        gemm(catr, fc0_W + (size_t)br * 480 * 256, xinb, 1024, 256, 480, 480, 256, 256,
             0, 0, 0, 1, 0, 1.f, fc0_b + br * 256, nullptr, 0, 0, 0);
        encoder(0, br, xinb);
    }
    // stages 1..5
    for (int s = 1; s < 6; ++s) {
        for (int br = 0; br < 2; ++br) {
            size_t wo = (size_t)(s - 1) * 2 + br;
            conv3x3_k<<<dim3(64, 16), 256, 0, stream>>>(cbuf[br][cur[br]], convW + wo * 256 * 256 * 9,
                                                        convB + wo * 256, cbuf[br][1 - cur[br]], 256);
            cur[br] ^= 1;
            pool_ct_k<<<(SPX * 256) / 256, 256, 0, stream>>>(cbuf[br][cur[br]], pooled, 256);
            concat_relu_k<<<SPX, 256, 0, stream>>>(pooled, 256, xb[br], 256, catr);
            gemm(catr, fc_W + wo * 512 * 256, xinb, 1024, 256, 512, 512, 256, 256,
                 0, 0, 0, 1, 0, 1.f, fc_b + wo * 256, nullptr, 0, 0, 0);
            encoder(s, br, xinb);
        }
    }
    // head
    absdiff_k<<<(SPX * 256) / 256, 256, 0, stream>>>(xb[0], xb[1], dabs, SPX * 256);
    gemm(dabs, head_W1, hhb, 1024, 128, 256, 256, 128, 128, 0, 0, 0, 1, 0, 1.f, head_b1, nullptr, 0, 0, 1);
    head2_k<<<4, 256, 0, stream>>>(hhb, head_W2, head_b2, outp);
}

// Round 2
// 3191.176 us; speedup vs baseline: 2.5046x; 2.5046x over previous
//
#include <hip/hip_runtime.h>
#include <hip/hip_bf16.h>
#include <math.h>

#define SPX 1024
#define HW 16384

typedef short short8 __attribute__((ext_vector_type(8)));
typedef float f32x4 __attribute__((ext_vector_type(4)));

__device__ inline short f2bf(float v){ union{ __hip_bfloat16 h; short s; } u; u.h = __float2bfloat16(v); return u.s; }
__device__ inline float bf2f(short s){ union{ __hip_bfloat16 h; short t; } u; u.t = s; return __bfloat162float(u.h); }

// ---------------- weight prep: transpose+convert conv weights to bf16 [co][tap][ci]; zero pad-line ----
__global__ __launch_bounds__(256) void prep_weights_k(const float* __restrict__ cwin, const float* __restrict__ cw,
                                                      short* __restrict__ wt0, short* __restrict__ wtl,
                                                      short* __restrict__ zbuf)
{
    long long idx = (long long)blockIdx.x * 256 + threadIdx.x;
    if (idx < 64) zbuf[idx] = 0;
    const long long n0 = 2LL * 256 * 2016;
    if (idx < n0) {
        int br = (int)(idx / (256 * 2016)); int rem = (int)(idx % (256 * 2016));
        int co = rem / 2016; int k = rem % 2016;
        int tap = k / 224, ci = k % 224;
        float v = cwin[((size_t)(br * 256 + co) * 224 + ci) * 9 + tap];
        wt0[idx] = f2bf(v);
    } else {
        long long i2 = idx - n0;
        if (i2 < 10LL * 256 * 2304) {
            int l = (int)(i2 / (256 * 2304)); int rem = (int)(i2 % (256 * 2304));
            int co = rem / 2304; int k = rem % 2304;
            int tap = k / 256, ci = k % 256;
            float v = cw[((size_t)(l * 256 + co) * 256 + ci) * 9 + tap];
            wtl[i2] = f2bf(v);
        }
    }
}

// ---------------- T1/T2 CHW fp32 -> HWC bf16 ----------------
__global__ __launch_bounds__(256) void prep_thwc_k(const float* __restrict__ T1, const float* __restrict__ T2,
                                                   short* __restrict__ thwc)
{
    long long idx = (long long)blockIdx.x * 256 + threadIdx.x;
    int br = (int)(idx / 3670016LL); int rem = (int)(idx % 3670016LL);
    int p = rem / 224, c = rem % 224;
    const float* src = br ? T2 : T1;
    thwc[idx] = f2bf(src[(size_t)c * HW + p]);
}

// ---------------- fused implicit-GEMM 3x3 conv, bf16 MFMA ----------------
// grid (2 co-blocks, 128 rows, 2 branches), 256 threads. Tile 128 px x 128 co, BK=32 ci.
__global__ __launch_bounds__(256) void conv_mfma_k(
    const short* __restrict__ inB, long long inStride,
    const short* __restrict__ wtB, long long wtStride,
    const float* __restrict__ biasB, long long biasStride,
    short* __restrict__ outB, long long outStride,
    const short* __restrict__ zbuf, int Cin)
{
    __shared__ short Asm[128 * 32];
    __shared__ short Bsm[128 * 32];
    int z = blockIdx.z;
    const short* in = inB + (size_t)z * inStride;
    const short* wt = wtB + (size_t)z * wtStride;
    const float* bias = biasB + (size_t)z * biasStride;
    short* out = outB + (size_t)z * outStride;
    int y = blockIdx.y;
    int co0 = blockIdx.x * 128;
    int tid = threadIdx.x;
    int lane = tid & 63, w = tid >> 6;
    int wm = w >> 1, wn = w & 1;
    int lrow = lane >> 2, lsub = (lane & 3) * 8;
    int Kw = 9 * Cin;
    f32x4 acc[4][4];
#pragma unroll
    for (int i = 0; i < 4; ++i)
#pragma unroll
        for (int j = 0; j < 4; ++j) acc[i][j] = (f32x4){0.f, 0.f, 0.f, 0.f};

    for (int tap = 0; tap < 9; ++tap) {
        int ky = tap / 3, kx = tap % 3;
        int gy = y + ky - 1;
        bool rowok = ((unsigned)gy < 128u);
        for (int c8 = 0; c8 < Cin; c8 += 32) {
#pragma unroll
            for (int s = 0; s < 2; ++s) {
                int r = w * 32 + s * 16 + lrow;
                int gx = r + kx - 1;
                const short* gp = (rowok && (unsigned)gx < 128u)
                    ? in + ((size_t)(gy * 128 + gx) * Cin + c8 + lsub)
                    : zbuf + lsub;
                __builtin_amdgcn_global_load_lds(
                    (const __attribute__((address_space(1))) void*)gp,
                    (__attribute__((address_space(3))) void*)(Asm + (w * 32 + s * 16) * 32),
                    16, 0, 0);
                const short* gq = wt + ((size_t)(co0 + r) * Kw + tap * Cin + c8 + lsub);
                __builtin_amdgcn_global_load_lds(
                    (const __attribute__((address_space(1))) void*)gq,
                    (__attribute__((address_space(3))) void*)(Bsm + (w * 32 + s * 16) * 32),
                    16, 0, 0);
            }
            __syncthreads();
            int mrow = lane & 15, kg = (lane >> 4) * 8;
            short8 af[4], bfr[4];
#pragma unroll
            for (int i = 0; i < 4; ++i)
                af[i] = *(const short8*)(Asm + (wm * 64 + i * 16 + mrow) * 32 + kg);
#pragma unroll
            for (int j = 0; j < 4; ++j)
                bfr[j] = *(const short8*)(Bsm + (wn * 64 + j * 16 + mrow) * 32 + kg);
#pragma unroll
            for (int i = 0; i < 4; ++i)
#pragma unroll
                for (int j = 0; j < 4; ++j)
                    acc[i][j] = __builtin_amdgcn_mfma_f32_16x16x32_bf16(af[i], bfr[j], acc[i][j], 0, 0, 0);
            __syncthreads();
        }
    }
    int ln15 = lane & 15, quad = lane >> 4;
    float bj[4];
#pragma unroll
    for (int j = 0; j < 4; ++j) bj[j] = bias[co0 + wn * 64 + j * 16 + ln15];
#pragma unroll
    for (int i = 0; i < 4; ++i) {
#pragma unroll
        for (int r = 0; r < 4; ++r) {
            int x = wm * 64 + i * 16 + quad * 4 + r;
            size_t po = ((size_t)y * 128 + x) * 256 + co0 + wn * 64 + ln15;
#pragma unroll
            for (int j = 0; j < 4; ++j)
                out[po + j * 16] = f2bf(acc[i][j][r] + bj[j]);
        }
    }
}

// ---------------- superpixel mean pooling from bf16 HWC ----------------
__global__ __launch_bounds__(256) void pool_bf16_k(const short* __restrict__ in, float* __restrict__ out,
                                                   int C, long long inZ, long long outZ)
{
    int z = blockIdx.y;
    int tid = blockIdx.x * 256 + threadIdx.x;
    int s = tid / C, c = tid - s * C;
    const short* p = in + (size_t)z * inZ + (size_t)s * C + c;
    float acc = 0.f;
#pragma unroll
    for (int j = 0; j < 16; ++j) acc += bf2f(p[(size_t)j * 1024 * C]);
    out[(size_t)z * outZ + (size_t)s * C + c] = acc * (1.f / 16.f);
}

// ---------------- generic fp32 GEMM with z = zo*ZH+zi batching ----------------
__global__ __launch_bounds__(256) void gemm_f32(const float* __restrict__ A, const float* __restrict__ B,
                                                float* C, int K, int lda, int ldb, int ldc, int ZH,
                                                long long sAo, long long sAi, long long sBo, long long sBi,
                                                long long sCo, long long sCi,
                                                int transB, float alpha,
                                                const float* __restrict__ bias, long long sBias,
                                                const float* addm, int ldadd, long long sAddo, long long sAddi,
                                                int act)
{
    __shared__ __align__(16) float As[16][68];
    __shared__ __align__(16) float Bs[16][68];
    int z = blockIdx.z, zo = z / ZH, zi = z - zo * ZH;
    const float* Ap = A + zo * sAo + zi * sAi;
    const float* Bp = B + zo * sBo + zi * sBi;
    float* Cp = C + zo * sCo + zi * sCi;
    const float* biasp = bias ? bias + zo * sBias : nullptr;
    const float* addp = addm ? addm + zo * sAddo + zi * sAddi : nullptr;
    int bn = blockIdx.x * 64, bm = blockIdx.y * 64;
    int tid = threadIdx.x;
    int tx = tid & 15, ty = tid >> 4;
    float acc[4][4];
#pragma unroll
    for (int r = 0; r < 4; ++r)
#pragma unroll
        for (int c = 0; c < 4; ++c) acc[r][c] = 0.f;

    int mmA = tid >> 2, kqA = (tid & 3) * 4;
    int kkB = tid >> 4, nqB = (tid & 15) * 4;
    int nnB = tid >> 2, kqB = (tid & 3) * 4;

    for (int k0 = 0; k0 < K; k0 += 16) {
        float4 av = *(const float4*)(Ap + (long long)(bm + mmA) * lda + k0 + kqA);
        As[kqA + 0][mmA] = av.x;
        As[kqA + 1][mmA] = av.y;
        As[kqA + 2][mmA] = av.z;
        As[kqA + 3][mmA] = av.w;
        if (!transB) {
            float4 bv = *(const float4*)(Bp + (long long)(k0 + kkB) * ldb + bn + nqB);
            *(float4*)&Bs[kkB][nqB] = bv;
        } else {
            float4 bv = *(const float4*)(Bp + (long long)(bn + nnB) * ldb + k0 + kqB);
            Bs[kqB + 0][nnB] = bv.x;
            Bs[kqB + 1][nnB] = bv.y;
            Bs[kqB + 2][nnB] = bv.z;
            Bs[kqB + 3][nnB] = bv.w;
        }
        __syncthreads();
#pragma unroll
        for (int kk = 0; kk < 16; ++kk) {
            float4 a4 = *(const float4*)&As[kk][ty * 4];
            float4 b4 = *(const float4*)&Bs[kk][tx * 4];
            float ar[4] = {a4.x, a4.y, a4.z, a4.w};
            float br[4] = {b4.x, b4.y, b4.z, b4.w};
#pragma unroll
            for (int r = 0; r < 4; ++r)
#pragma unroll
                for (int c = 0; c < 4; ++c) acc[r][c] += ar[r] * br[c];
        }
        __syncthreads();
    }
#pragma unroll
    for (int r = 0; r < 4; ++r) {
        int row = bm + ty * 4 + r;
        float4 vv;
        float* vp = &vv.x;
#pragma unroll
        for (int c = 0; c < 4; ++c) {
            int col = bn + tx * 4 + c;
            float v = alpha * acc[r][c];
            if (biasp) v += biasp[col];
            if (addp) v += addp[(long long)row * ldadd + col];
            if (act == 1) v = fmaxf(v, 0.f);
            else if (act == 2) v = 0.5f * v * (1.f + erff(v * 0.70710678118f));
            vp[c] = v;
        }
        *(float4*)(Cp + (long long)row * ldc + bn + tx * 4) = vv;
    }
}

// ---------------- layernorm over 256, z-batched [2][1024][256] streams ----------------
__global__ __launch_bounds__(256) void ln_k(const float* __restrict__ xin, const float* __restrict__ pos,
                                            float* __restrict__ xout, const float* __restrict__ g,
                                            const float* __restrict__ b, float* __restrict__ hout)
{
    int row = blockIdx.x, z = blockIdx.y, tid = threadIdx.x;
    __shared__ float red[256];
    size_t o = (size_t)z * 262144 + (size_t)row * 256 + tid;
    float v = xin[o];
    if (pos) v += pos[o];
    if (xout) xout[o] = v;
    red[tid] = v;
    __syncthreads();
    for (int st = 128; st > 0; st >>= 1) {
        if (tid < st) red[tid] += red[tid + st];
        __syncthreads();
    }
    float m = red[0] * (1.f / 256.f);
    __syncthreads();
    float d = v - m;
    red[tid] = d * d;
    __syncthreads();
    for (int st = 128; st > 0; st >>= 1) {
        if (tid < st) red[tid] += red[tid + st];
        __syncthreads();
    }
    float var = red[0] * (1.f / 256.f);
    float rs = rsqrtf(var + 1e-5f);
    hout[o] = d * rs * g[z * 256 + tid] + b[z * 256 + tid];
}

// ---------------- row softmax over 1024 cols ----------------
__global__ __launch_bounds__(256) void softmax_k(float* __restrict__ d)
{
    int row = blockIdx.x, tid = threadIdx.x;
    float* p = d + (long long)row * 1024;
    float v[4];
#pragma unroll
    for (int j = 0; j < 4; ++j) v[j] = p[tid + 256 * j];
    float m = fmaxf(fmaxf(v[0], v[1]), fmaxf(v[2], v[3]));
    __shared__ float red[256];
    red[tid] = m;
    __syncthreads();
    for (int st = 128; st > 0; st >>= 1) {
        if (tid < st) red[tid] = fmaxf(red[tid], red[tid + st]);
        __syncthreads();
    }
    m = red[0];
    __syncthreads();
    float sum = 0.f;
#pragma unroll
    for (int j = 0; j < 4; ++j) { v[j] = expf(v[j] - m); sum += v[j]; }
    red[tid] = sum;
    __syncthreads();
    for (int st = 128; st > 0; st >>= 1) {
        if (tid < st) red[tid] += red[tid + st];
        __syncthreads();
    }
    float inv = 1.f / red[0];
#pragma unroll
    for (int j = 0; j < 4; ++j) p[tid + 256 * j] = v[j] * inv;
}

// ---------------- concat two row blocks + relu, z-batched ----------------
__global__ __launch_bounds__(256) void concat_relu_k(const float* __restrict__ a, int ca, long long aZ,
                                                     const float* __restrict__ b, int cb, long long bZ,
                                                     float* __restrict__ out, long long oZ)
{
    int row = blockIdx.x, z = blockIdx.y;
    int n = ca + cb;
    const float* ap = a + (size_t)z * aZ + (size_t)row * ca;
    const float* bp = b + (size_t)z * bZ + (size_t)row * cb;
    float* op = out + (size_t)z * oZ + (size_t)row * n;
    for (int col = threadIdx.x; col < n; col += 256) {
        float v = (col < ca) ? ap[col] : bp[col - ca];
        op[col] = fmaxf(v, 0.f);
    }
}

__global__ __launch_bounds__(256) void absdiff_k(const float* __restrict__ a, const float* __restrict__ b,
                                                 float* __restrict__ o, int n)
{
    int i = blockIdx.x * 256 + threadIdx.x;
    if (i < n) o[i] = fabsf(a[i] - b[i]);
}

__global__ __launch_bounds__(256) void head2_k(const float* __restrict__ hh, const float* __restrict__ W2,
                                               const float* __restrict__ b2, float* __restrict__ out)
{
    int s = blockIdx.x * 256 + threadIdx.x;
    if (s >= SPX) return;
    float l0 = b2[0], l1 = b2[1];
    const float* hp = hh + (size_t)s * 128;
    for (int k = 0; k < 128; ++k) {
        float v = hp[k];
        l0 += v * W2[k * 2];
        l1 += v * W2[k * 2 + 1];
    }
    float m = fmaxf(l0, l1);
    float e0 = expf(l0 - m), e1 = expf(l1 - m);
    float inv = 1.f / (e0 + e1);
    out[s * 2] = e0 * inv;
    out[s * 2 + 1] = e1 * inv;
}

extern "C" void kernel_launch(void* const* d_in, const int* in_sizes, int n_in,
                              void* d_out, int out_size, void* d_ws, size_t ws_size,
                              hipStream_t stream)
{
    (void)in_sizes; (void)n_in; (void)out_size; (void)ws_size;
    const float* T1 = (const float*)d_in[0];
    const float* T2 = (const float*)d_in[1];
    const float* Abias = (const float*)d_in[3];
    const float* convW_in = (const float*)d_in[4];
    const float* convB_in = (const float*)d_in[5];
    const float* convW = (const float*)d_in[6];
    const float* convB = (const float*)d_in[7];
    const float* fc0_W = (const float*)d_in[8];
    const float* fc0_b = (const float*)d_in[9];
    const float* fc_W = (const float*)d_in[10];
    const float* fc_b = (const float*)d_in[11];
    const float* pos = (const float*)d_in[12];
    const float* ln1_g = (const float*)d_in[13];
    const float* ln1_b = (const float*)d_in[14];
    const float* qkv_W = (const float*)d_in[15];
    const float* out_W = (const float*)d_in[16];
    const float* out_b = (const float*)d_in[17];
    const float* ln2_g = (const float*)d_in[18];
    const float* ln2_b = (const float*)d_in[19];
    const float* ff_W1 = (const float*)d_in[20];
    const float* ff_b1 = (const float*)d_in[21];
    const float* ff_W2 = (const float*)d_in[22];
    const float* ff_b2 = (const float*)d_in[23];
    const float* head_W1 = (const float*)d_in[24];
    const float* head_b1 = (const float*)d_in[25];
    const float* head_W2 = (const float*)d_in[26];
    const float* head_b2 = (const float*)d_in[27];
    float* outp = (float*)d_out;

    char* wp = (char*)d_ws;
    auto alloc = [&](size_t bytes) { char* p = wp; wp += (bytes + 255) & ~(size_t)255; return p; };
    short* cbufA = (short*)alloc(16777216);
    short* cbufB = (short*)alloc(16777216);
    short* wt0 = (short*)alloc(2064384);
    short* wtl = (short*)alloc(11796480);
    short* zbuf = (short*)alloc(256);
    float* dots = (float*)alloc(33554432);
    short* thwc = (short*)dots;       // alias: thwc dead before dots first written
    float* LSb = (float*)alloc(1835008);
    float* pooled = (float*)alloc(2097152);
    float* catr = (float*)alloc(4194304);
    float* xinb = (float*)alloc(2097152);
    float* xbuf = (float*)alloc(2097152);
    float* hbuf = (float*)alloc(2097152);
    float* qkvb = (float*)alloc(12582912);
    float* obuf = (float*)alloc(4194304);
    float* h2b = (float*)alloc(2097152);
    float* ffhb = (float*)alloc(4194304);
    float* dabs = (float*)alloc(1048576);
    float* hhb = (float*)alloc(524288);

    auto gemm = [&](const float* A, const float* B, float* C, int M, int N, int K,
                    int lda, int ldb, int ldc, int Z, int ZH,
                    long long sAo, long long sAi, long long sBo, long long sBi,
                    long long sCo, long long sCi,
                    int transB, float alpha, const float* bias, long long sBias,
                    const float* addm, int ldadd, long long sAddo, long long sAddi, int act) {
        dim3 g((unsigned)(N / 64), (unsigned)(M / 64), (unsigned)Z);
        gemm_f32<<<g, dim3(256), 0, stream>>>(A, B, C, K, lda, ldb, ldc, ZH, sAo, sAi, sBo, sBi,
                                              sCo, sCi, transB, alpha, bias, sBias,
                                              addm, ldadd, sAddo, sAddi, act);
    };

    auto encoder = [&](int s) {
        const float* posb = pos + (size_t)s * 524288;
        ln_k<<<dim3(1024, 2), 256, 0, stream>>>(xinb, posb, xbuf, ln1_g + s * 512, ln1_b + s * 512, hbuf);
        gemm(hbuf, qkv_W + (size_t)s * 786432, qkvb, 1024, 1536, 256, 256, 1536, 1536, 2, 1,
             262144, 0, 393216, 0, 1572864, 0, 0, 1.f, nullptr, 0, nullptr, 0, 0, 0, 0);
        for (int br = 0; br < 2; ++br) {
            const float* qb = qkvb + (size_t)br * 1572864;
            gemm(qb, qb + 512, dots, 1024, 1024, 64, 1536, 1536, 1024, 8, 8,
                 0, 64, 0, 64, 0, 1048576, 1, 0.125f, nullptr, 0, Abias, 1024, 0, 0, 0);
            softmax_k<<<8192, 256, 0, stream>>>(dots);
            gemm(dots, qb + 1024, obuf + (size_t)br * 524288, 1024, 64, 1024, 1024, 1536, 512, 8, 8,
                 0, 1048576, 0, 64, 0, 64, 0, 1.f, nullptr, 0, nullptr, 0, 0, 0, 0);
        }
        gemm(obuf, out_W + (size_t)s * 262144, xbuf, 1024, 256, 512, 512, 256, 256, 2, 1,
             524288, 0, 131072, 0, 262144, 0, 0, 1.f, out_b + s * 512, 256, xbuf, 256, 262144, 0, 0);
        ln_k<<<dim3(1024, 2), 256, 0, stream>>>(xbuf, nullptr, nullptr, ln2_g + s * 512, ln2_b + s * 512, h2b);
        gemm(h2b, ff_W1 + (size_t)s * 262144, ffhb, 1024, 512, 256, 256, 512, 512, 2, 1,
             262144, 0, 131072, 0, 524288, 0, 0, 1.f, ff_b1 + s * 1024, 512, nullptr, 0, 0, 0, 2);
        gemm(ffhb, ff_W2 + (size_t)s * 262144, xbuf, 1024, 256, 512, 512, 256, 256, 2, 1,
             524288, 0, 131072, 0, 262144, 0, 0, 1.f, ff_b2 + s * 512, 256, xbuf, 256, 262144, 0, 0);
    };

    // prep: weights -> bf16 [co][tap][ci]; T -> HWC bf16; zero pad-line
    prep_weights_k<<<27072, 256, 0, stream>>>(convW_in, convW, wt0, wtl, zbuf);
    prep_thwc_k<<<28672, 256, 0, stream>>>(T1, T2, thwc);
    // LS = pooled raw inputs (from bf16 HWC)
    pool_bf16_k<<<dim3(896, 2), 256, 0, stream>>>(thwc, LSb, 224, 3670016LL, 229376LL);
    // conv layer 0 (224 -> 256), both branches
    conv_mfma_k<<<dim3(2, 128, 2), 256, 0, stream>>>(thwc, 3670016LL, wt0, 516096LL, convB_in, 256LL,
                                                     cbufA, 4194304LL, zbuf, 224);
    short* cur = cbufA; short* nxt = cbufB;
    for (int s = 0; s < 6; ++s) {
        if (s > 0) {
            conv_mfma_k<<<dim3(2, 128, 2), 256, 0, stream>>>(cur, 4194304LL, wtl + (size_t)(s - 1) * 2 * 589824,
                                                             589824LL, convB + (size_t)(s - 1) * 512, 256LL,
                                                             nxt, 4194304LL, zbuf, 256);
            short* t = cur; cur = nxt; nxt = t;
        }
        pool_bf16_k<<<dim3(1024, 2), 256, 0, stream>>>(cur, pooled, 256, 4194304LL, 262144LL);
        if (s == 0) {
            concat_relu_k<<<dim3(1024, 2), 256, 0, stream>>>(pooled, 256, 262144LL, LSb, 224, 229376LL, catr, 491520LL);
            gemm(catr, fc0_W, xinb, 1024, 256, 480, 480, 256, 256, 2, 1,
                 491520, 0, 122880, 0, 262144, 0, 0, 1.f, fc0_b, 256, nullptr, 0, 0, 0, 0);
        } else {
            concat_relu_k<<<dim3(1024, 2), 256, 0, stream>>>(pooled, 256, 262144LL, xbuf, 256, 262144LL, catr, 524288LL);
            gemm(catr, fc_W + (size_t)(s - 1) * 262144, xinb, 1024, 256, 512, 512, 256, 256, 2, 1,
                 524288, 0, 131072, 0, 262144, 0, 0, 1.f, fc_b + (size_t)(s - 1) * 512, 256, nullptr, 0, 0, 0, 0);
        }
        encoder(s);
    }
    // head
    absdiff_k<<<1024, 256, 0, stream>>>(xbuf, xbuf + 262144, dabs, 262144);
    gemm(dabs, head_W1, hhb, 1024, 128, 256, 256, 128, 128, 1, 1,
         0, 0, 0, 0, 0, 0, 0, 1.f, head_b1, 0, nullptr, 0, 0, 0, 1);
    head2_k<<<4, 256, 0, stream>>>(hhb, head_W2, head_b2, outp);
}

// Round 3
// 1828.793 us; speedup vs baseline: 4.3705x; 1.7450x over previous
//
#include <hip/hip_runtime.h>
#include <hip/hip_bf16.h>
#include <math.h>

#define SPX 1024
#define HW 16384

typedef short short8 __attribute__((ext_vector_type(8)));
typedef short short4v __attribute__((ext_vector_type(4)));
typedef float f32x4 __attribute__((ext_vector_type(4)));

__device__ inline short f2bf(float v){ union{ __hip_bfloat16 h; short s; } u; u.h = __float2bfloat16(v); return u.s; }
__device__ inline float bf2f(short s){ union{ __hip_bfloat16 h; short t; } u; u.t = s; return __bfloat162float(u.h); }

// ---------------- conv weight prep -> bf16 [co][tap][ci]; zero pad-line ----------------
__global__ __launch_bounds__(256) void prep_weights_k(const float* __restrict__ cwin, const float* __restrict__ cw,
                                                      short* __restrict__ wt0, short* __restrict__ wtl,
                                                      short* __restrict__ zbuf)
{
    long long idx = (long long)blockIdx.x * 256 + threadIdx.x;
    if (idx < 64) zbuf[idx] = 0;
    const long long n0 = 2LL * 256 * 2016;
    if (idx < n0) {
        int br = (int)(idx / (256 * 2016)); int rem = (int)(idx % (256 * 2016));
        int co = rem / 2016; int k = rem % 2016;
        int tap = k / 224, ci = k % 224;
        wt0[idx] = f2bf(cwin[((size_t)(br * 256 + co) * 224 + ci) * 9 + tap]);
    } else {
        long long i2 = idx - n0;
        if (i2 < 10LL * 256 * 2304) {
            int l = (int)(i2 / (256 * 2304)); int rem = (int)(i2 % (256 * 2304));
            int co = rem / 2304; int k = rem % 2304;
            int tap = k / 256, ci = k % 256;
            wtl[i2] = f2bf(cw[((size_t)(l * 256 + co) * 256 + ci) * 9 + tap]);
        }
    }
}

// ---------------- T1/T2 CHW fp32 -> HWC bf16 ----------------
__global__ __launch_bounds__(256) void prep_thwc_k(const float* __restrict__ T1, const float* __restrict__ T2,
                                                   short* __restrict__ thwc)
{
    long long idx = (long long)blockIdx.x * 256 + threadIdx.x;
    int br = (int)(idx / 3670016LL); int rem = (int)(idx % 3670016LL);
    int p = rem / 224, c = rem % 224;
    const float* src = br ? T2 : T1;
    thwc[idx] = f2bf(src[(size_t)c * HW + p]);
}

// ---------------- generic fp32 [K][N] -> bf16 [N][K] transpose (32x32 LDS tiles) ----------------
__global__ __launch_bounds__(256) void transpose_w_k(const float* __restrict__ src, short* __restrict__ dst,
                                                     int K, int N)
{
    __shared__ float tile[32][33];
    int n0 = blockIdx.x * 32, k0 = blockIdx.y * 32, b = blockIdx.z;
    const float* s = src + (size_t)b * K * N;
    short* d = dst + (size_t)b * K * N;
    int tid = threadIdx.x;
    int r = tid >> 3, c4 = (tid & 7) * 4;
    float4 v = *(const float4*)(s + (size_t)(k0 + r) * N + n0 + c4);
    tile[r][c4 + 0] = v.x; tile[r][c4 + 1] = v.y; tile[r][c4 + 2] = v.z; tile[r][c4 + 3] = v.w;
    __syncthreads();
    short4v o;
#pragma unroll
    for (int i = 0; i < 4; ++i) o[i] = f2bf(tile[c4 + i][r]);
    *(short4v*)(d + (size_t)(n0 + r) * K + k0 + c4) = o;
}

// ---------------- fused implicit-GEMM 3x3 conv, bf16 MFMA ----------------
__global__ __launch_bounds__(256) void conv_mfma_k(
    const short* __restrict__ inB, long long inStride,
    const short* __restrict__ wtB, long long wtStride,
    const float* __restrict__ biasB, long long biasStride,
    short* __restrict__ outB, long long outStride,
    const short* __restrict__ zbuf, int Cin)
{
    __shared__ short Asm[128 * 32];
    __shared__ short Bsm[128 * 32];
    int z = blockIdx.z;
    const short* in = inB + (size_t)z * inStride;
    const short* wt = wtB + (size_t)z * wtStride;
    const float* bias = biasB + (size_t)z * biasStride;
    short* out = outB + (size_t)z * outStride;
    int y = blockIdx.y;
    int co0 = blockIdx.x * 128;
    int tid = threadIdx.x;
    int lane = tid & 63, w = tid >> 6;
    int wm = w >> 1, wn = w & 1;
    int lrow = lane >> 2, lsub = (lane & 3) * 8;
    int Kw = 9 * Cin;
    f32x4 acc[4][4];
#pragma unroll
    for (int i = 0; i < 4; ++i)
#pragma unroll
        for (int j = 0; j < 4; ++j) acc[i][j] = (f32x4){0.f, 0.f, 0.f, 0.f};

    for (int tap = 0; tap < 9; ++tap) {
        int ky = tap / 3, kx = tap % 3;
        int gy = y + ky - 1;
        bool rowok = ((unsigned)gy < 128u);
        for (int c8 = 0; c8 < Cin; c8 += 32) {
#pragma unroll
            for (int s = 0; s < 2; ++s) {
                int r = w * 32 + s * 16 + lrow;
                int gx = r + kx - 1;
                const short* gp = (rowok && (unsigned)gx < 128u)
                    ? in + ((size_t)(gy * 128 + gx) * Cin + c8 + lsub)
                    : zbuf + lsub;
                __builtin_amdgcn_global_load_lds(
                    (const __attribute__((address_space(1))) void*)gp,
                    (__attribute__((address_space(3))) void*)(Asm + (w * 32 + s * 16) * 32),
                    16, 0, 0);
                const short* gq = wt + ((size_t)(co0 + r) * Kw + tap * Cin + c8 + lsub);
                __builtin_amdgcn_global_load_lds(
                    (const __attribute__((address_space(1))) void*)gq,
                    (__attribute__((address_space(3))) void*)(Bsm + (w * 32 + s * 16) * 32),
                    16, 0, 0);
            }
            __syncthreads();
            int mrow = lane & 15, kg = (lane >> 4) * 8;
            short8 af[4], bfr[4];
#pragma unroll
            for (int i = 0; i < 4; ++i)
                af[i] = *(const short8*)(Asm + (wm * 64 + i * 16 + mrow) * 32 + kg);
#pragma unroll
            for (int j = 0; j < 4; ++j)
                bfr[j] = *(const short8*)(Bsm + (wn * 64 + j * 16 + mrow) * 32 + kg);
#pragma unroll
            for (int i = 0; i < 4; ++i)
#pragma unroll
                for (int j = 0; j < 4; ++j)
                    acc[i][j] = __builtin_amdgcn_mfma_f32_16x16x32_bf16(af[i], bfr[j], acc[i][j], 0, 0, 0);
            __syncthreads();
        }
    }
    int ln15 = lane & 15, quad = lane >> 4;
    float bj[4];
#pragma unroll
    for (int j = 0; j < 4; ++j) bj[j] = bias[co0 + wn * 64 + j * 16 + ln15];
#pragma unroll
    for (int i = 0; i < 4; ++i) {
#pragma unroll
        for (int r = 0; r < 4; ++r) {
            int x = wm * 64 + i * 16 + quad * 4 + r;
            size_t po = ((size_t)y * 128 + x) * 256 + co0 + wn * 64 + ln15;
#pragma unroll
            for (int j = 0; j < 4; ++j)
                out[po + j * 16] = f2bf(acc[i][j][r] + bj[j]);
        }
    }
}

// ---------------- bf16 MFMA GEMM: C = act(A @ Bt^T + bias + addm), 128x128 tile, BK=32 ----------------
// A: bf16 MxK (lda); Bt: bf16 NxK row-major. Outputs fp32 (Cf) and/or bf16 (Cb). grid (N/128, M/128, Z)
__global__ __launch_bounds__(256) void gemm_bf16_k(
    const short* __restrict__ A, long long sA, int lda,
    const short* __restrict__ Bt, long long sB, int K,
    float* Cf, long long sCf, short* Cb, long long sCb, int ldc,
    const float* __restrict__ bias, long long sBias,
    const float* addm, long long sAdd, int ldadd, int act)
{
    __shared__ short Asm[128 * 32];
    __shared__ short Bsm[128 * 32];
    int z = blockIdx.z;
    const short* Ap = A + (size_t)z * sA;
    const short* Bp = Bt + (size_t)z * sB;
    const float* biasp = bias ? bias + (size_t)z * sBias : nullptr;
    const float* addp = addm ? addm + (size_t)z * sAdd : nullptr;
    int bn = blockIdx.x * 128, bm = blockIdx.y * 128;
    int tid = threadIdx.x;
    int lane = tid & 63, w = tid >> 6;
    int wm = w >> 1, wn = w & 1;
    int lrow = lane >> 2, lsub = (lane & 3) * 8;
    f32x4 acc[4][4];
#pragma unroll
    for (int i = 0; i < 4; ++i)
#pragma unroll
        for (int j = 0; j < 4; ++j) acc[i][j] = (f32x4){0.f, 0.f, 0.f, 0.f};

    for (int k0 = 0; k0 < K; k0 += 32) {
#pragma unroll
        for (int s = 0; s < 2; ++s) {
            int r = w * 32 + s * 16 + lrow;
            const short* gp = Ap + (size_t)(bm + r) * lda + k0 + lsub;
            __builtin_amdgcn_global_load_lds(
                (const __attribute__((address_space(1))) void*)gp,
                (__attribute__((address_space(3))) void*)(Asm + (w * 32 + s * 16) * 32), 16, 0, 0);
            const short* gq = Bp + (size_t)(bn + r) * K + k0 + lsub;
            __builtin_amdgcn_global_load_lds(
                (const __attribute__((address_space(1))) void*)gq,
                (__attribute__((address_space(3))) void*)(Bsm + (w * 32 + s * 16) * 32), 16, 0, 0);
        }
        __syncthreads();
        int mrow = lane & 15, kg = (lane >> 4) * 8;
        short8 af[4], bfr[4];
#pragma unroll
        for (int i = 0; i < 4; ++i)
            af[i] = *(const short8*)(Asm + (wm * 64 + i * 16 + mrow) * 32 + kg);
#pragma unroll
        for (int j = 0; j < 4; ++j)
            bfr[j] = *(const short8*)(Bsm + (wn * 64 + j * 16 + mrow) * 32 + kg);
#pragma unroll
        for (int i = 0; i < 4; ++i)
#pragma unroll
            for (int j = 0; j < 4; ++j)
                acc[i][j] = __builtin_amdgcn_mfma_f32_16x16x32_bf16(af[i], bfr[j], acc[i][j], 0, 0, 0);
        __syncthreads();
    }
    int ln15 = lane & 15, quad = lane >> 4;
    float* Cfp = Cf ? Cf + (size_t)z * sCf : nullptr;
    short* Cbp = Cb ? Cb + (size_t)z * sCb : nullptr;
#pragma unroll
    for (int i = 0; i < 4; ++i) {
#pragma unroll
        for (int r = 0; r < 4; ++r) {
            int row = bm + wm * 64 + i * 16 + quad * 4 + r;
            long long ro = (long long)row * ldc;
#pragma unroll
            for (int j = 0; j < 4; ++j) {
                int col = bn + wn * 64 + j * 16 + ln15;
                float v = acc[i][j][r];
                if (biasp) v += biasp[col];
                if (addp) v += addp[(long long)row * ldadd + col];
                if (act == 1) v = fmaxf(v, 0.f);
                else if (act == 2) v = 0.5f * v * (1.f + erff(v * 0.70710678118f));
                if (Cfp) Cfp[ro + col] = v;
                if (Cbp) Cbp[ro + col] = f2bf(v);
            }
        }
    }
}

// ---------------- fused flash attention: per block (64 Q-rows, head, branch) ----------------
__global__ __launch_bounds__(256) void flash_k(const short* __restrict__ qkv, const float* __restrict__ Abias,
                                               short* __restrict__ obuf)
{
    __shared__ short Qs[64 * 72];
    __shared__ short Ks[128 * 72];
    __shared__ short Vt[64 * 136];
    __shared__ short Ps[64 * 136];
    int q0 = blockIdx.x * 64, h = blockIdx.y, br = blockIdx.z;
    const short* qb = qkv + (size_t)br * 1572864;
    int tid = threadIdx.x;
    int lane = tid & 63, w = tid >> 6;
    int ln15 = lane & 15, quad = lane >> 4;
    // stage Q tile (64x64)
    {
        int row = tid & 63, c0 = (tid >> 6) * 16;
        const short* src = qb + (size_t)(q0 + row) * 1536 + h * 64 + c0;
        *(short8*)(Qs + row * 72 + c0) = *(const short8*)src;
        *(short8*)(Qs + row * 72 + c0 + 8) = *(const short8*)(src + 8);
    }
    f32x4 Oc[4];
    float mrow[4], lsum[4];
#pragma unroll
    for (int i = 0; i < 4; ++i) { Oc[i] = (f32x4){0.f, 0.f, 0.f, 0.f}; mrow[i] = -1e30f; lsum[i] = 0.f; }

    for (int j = 0; j < 8; ++j) {
        int k0 = j * 128;
        // stage K (128x64, padded 72) and V^T (64x128, padded 136)
        {
            int row = tid & 127, half = tid >> 7;
            const short* ks = qb + (size_t)(k0 + row) * 1536 + 512 + h * 64 + half * 32;
#pragma unroll
            for (int g = 0; g < 4; ++g)
                *(short8*)(Ks + row * 72 + half * 32 + g * 8) = *(const short8*)(ks + g * 8);
            const short* vs = qb + (size_t)(k0 + row) * 1536 + 1024 + h * 64 + half * 32;
#pragma unroll
            for (int g = 0; g < 4; ++g) {
                short8 vv = *(const short8*)(vs + g * 8);
#pragma unroll
                for (int e = 0; e < 8; ++e)
                    Vt[(half * 32 + g * 8 + e) * 136 + row] = vv[e];
            }
        }
        __syncthreads();
        // S = Q K^T (wave: 16 q-rows x 128 cols)
        short8 aq[2];
#pragma unroll
        for (int g = 0; g < 2; ++g)
            aq[g] = *(const short8*)(Qs + (w * 16 + ln15) * 72 + g * 32 + quad * 8);
        f32x4 Sf[8];
#pragma unroll
        for (int nf = 0; nf < 8; ++nf) Sf[nf] = (f32x4){0.f, 0.f, 0.f, 0.f};
#pragma unroll
        for (int nf = 0; nf < 8; ++nf)
#pragma unroll
            for (int g = 0; g < 2; ++g) {
                short8 bk = *(const short8*)(Ks + (nf * 16 + ln15) * 72 + g * 32 + quad * 8);
                Sf[nf] = __builtin_amdgcn_mfma_f32_16x16x32_bf16(aq[g], bk, Sf[nf], 0, 0, 0);
            }
        // scale + bias + online softmax
        float rm[4] = {-1e30f, -1e30f, -1e30f, -1e30f};
#pragma unroll
        for (int nf = 0; nf < 8; ++nf)
#pragma unroll
            for (int r = 0; r < 4; ++r) {
                float v = Sf[nf][r] * 0.125f +
                          Abias[(size_t)(q0 + w * 16 + quad * 4 + r) * 1024 + k0 + nf * 16 + ln15];
                Sf[nf][r] = v;
                rm[r] = fmaxf(rm[r], v);
            }
#pragma unroll
        for (int r = 0; r < 4; ++r)
#pragma unroll
            for (int msk = 1; msk < 16; msk <<= 1)
                rm[r] = fmaxf(rm[r], __shfl_xor(rm[r], msk));
        float alpha[4], rs[4];
#pragma unroll
        for (int r = 0; r < 4; ++r) {
            float mnew = fmaxf(mrow[r], rm[r]);
            alpha[r] = expf(mrow[r] - mnew);
            mrow[r] = mnew;
            rs[r] = 0.f;
        }
#pragma unroll
        for (int nf = 0; nf < 8; ++nf)
#pragma unroll
            for (int r = 0; r < 4; ++r) {
                float p = expf(Sf[nf][r] - mrow[r]);
                Sf[nf][r] = p;
                rs[r] += p;
            }
#pragma unroll
        for (int r = 0; r < 4; ++r) {
#pragma unroll
            for (int msk = 1; msk < 16; msk <<= 1)
                rs[r] += __shfl_xor(rs[r], msk);
            lsum[r] = lsum[r] * alpha[r] + rs[r];
        }
#pragma unroll
        for (int nf = 0; nf < 4; ++nf)
#pragma unroll
            for (int r = 0; r < 4; ++r) Oc[nf][r] *= alpha[r];
        // P -> LDS (bf16, C-layout scatter)
#pragma unroll
        for (int nf = 0; nf < 8; ++nf)
#pragma unroll
            for (int r = 0; r < 4; ++r)
                Ps[(w * 16 + quad * 4 + r) * 136 + nf * 16 + ln15] = f2bf(Sf[nf][r]);
        __syncthreads();
        // O += P V
#pragma unroll
        for (int g = 0; g < 4; ++g) {
            short8 ap = *(const short8*)(Ps + (w * 16 + ln15) * 136 + g * 32 + quad * 8);
#pragma unroll
            for (int nf = 0; nf < 4; ++nf) {
                short8 bv = *(const short8*)(Vt + (nf * 16 + ln15) * 136 + g * 32 + quad * 8);
                Oc[nf] = __builtin_amdgcn_mfma_f32_16x16x32_bf16(ap, bv, Oc[nf], 0, 0, 0);
            }
        }
        __syncthreads();
    }
#pragma unroll
    for (int nf = 0; nf < 4; ++nf)
#pragma unroll
        for (int r = 0; r < 4; ++r) {
            int row = q0 + w * 16 + quad * 4 + r;
            obuf[(size_t)br * 524288 + (size_t)row * 512 + h * 64 + nf * 16 + ln15] =
                f2bf(Oc[nf][r] / lsum[r]);
        }
}

// ---------------- superpixel mean pooling from bf16 HWC ----------------
__global__ __launch_bounds__(256) void pool_bf16_k(const short* __restrict__ in, float* __restrict__ out,
                                                   int C, long long inZ, long long outZ)
{
    int z = blockIdx.y;
    int tid = blockIdx.x * 256 + threadIdx.x;
    int s = tid / C, c = tid - s * C;
    const short* p = in + (size_t)z * inZ + (size_t)s * C + c;
    float acc = 0.f;
#pragma unroll
    for (int j = 0; j < 16; ++j) acc += bf2f(p[(size_t)j * 1024 * C]);
    out[(size_t)z * outZ + (size_t)s * C + c] = acc * (1.f / 16.f);
}

// ---------------- layernorm over 256; fp32 stream out + bf16 normalized out ----------------
__global__ __launch_bounds__(256) void ln_k(const float* __restrict__ xin, const float* __restrict__ pos,
                                            float* __restrict__ xout, const float* __restrict__ g,
                                            const float* __restrict__ b, short* __restrict__ hout)
{
    int row = blockIdx.x, z = blockIdx.y, tid = threadIdx.x;
    __shared__ float red[256];
    size_t o = (size_t)z * 262144 + (size_t)row * 256 + tid;
    float v = xin[o];
    if (pos) v += pos[o];
    if (xout) xout[o] = v;
    red[tid] = v;
    __syncthreads();
    for (int st = 128; st > 0; st >>= 1) {
        if (tid < st) red[tid] += red[tid + st];
        __syncthreads();
    }
    float m = red[0] * (1.f / 256.f);
    __syncthreads();
    float d = v - m;
    red[tid] = d * d;
    __syncthreads();
    for (int st = 128; st > 0; st >>= 1) {
        if (tid < st) red[tid] += red[tid + st];
        __syncthreads();
    }
    float rs = rsqrtf(red[0] * (1.f / 256.f) + 1e-5f);
    hout[o] = f2bf(d * rs * g[z * 256 + tid] + b[z * 256 + tid]);
}

// ---------------- concat + relu -> bf16 ----------------
__global__ __launch_bounds__(256) void concat_relu_k(const float* __restrict__ a, int ca, long long aZ,
                                                     const float* __restrict__ b, int cb, long long bZ,
                                                     short* __restrict__ out, long long oZ)
{
    int row = blockIdx.x, z = blockIdx.y;
    int n = ca + cb;
    const float* ap = a + (size_t)z * aZ + (size_t)row * ca;
    const float* bp = b + (size_t)z * bZ + (size_t)row * cb;
    short* op = out + (size_t)z * oZ + (size_t)row * n;
    for (int col = threadIdx.x; col < n; col += 256) {
        float v = (col < ca) ? ap[col] : bp[col - ca];
        op[col] = f2bf(fmaxf(v, 0.f));
    }
}

__global__ __launch_bounds__(256) void absdiff_k(const float* __restrict__ a, const float* __restrict__ b,
                                                 float* __restrict__ o, int n)
{
    int i = blockIdx.x * 256 + threadIdx.x;
    if (i < n) o[i] = fabsf(a[i] - b[i]);
}

// ---------------- fp32 head GEMM (64x64 tiles) ----------------
__global__ __launch_bounds__(256) void gemm_f32_head(const float* __restrict__ A, const float* __restrict__ B,
                                                     float* __restrict__ C, int K, int lda, int ldb, int ldc,
                                                     const float* __restrict__ bias, int act)
{
    __shared__ __align__(16) float As[16][68];
    __shared__ __align__(16) float Bs[16][68];
    int bn = blockIdx.x * 64, bm = blockIdx.y * 64;
    int tid = threadIdx.x;
    int tx = tid & 15, ty = tid >> 4;
    float acc[4][4];
#pragma unroll
    for (int r = 0; r < 4; ++r)
#pragma unroll
        for (int c = 0; c < 4; ++c) acc[r][c] = 0.f;
    int mmA = tid >> 2, kqA = (tid & 3) * 4;
    int kkB = tid >> 4, nqB = (tid & 15) * 4;
    for (int k0 = 0; k0 < K; k0 += 16) {
        float4 av = *(const float4*)(A + (long long)(bm + mmA) * lda + k0 + kqA);
        As[kqA + 0][mmA] = av.x; As[kqA + 1][mmA] = av.y;
        As[kqA + 2][mmA] = av.z; As[kqA + 3][mmA] = av.w;
        *(float4*)&Bs[kkB][nqB] = *(const float4*)(B + (long long)(k0 + kkB) * ldb + bn + nqB);
        __syncthreads();
#pragma unroll
        for (int kk = 0; kk < 16; ++kk) {
            float4 a4 = *(const float4*)&As[kk][ty * 4];
            float4 b4 = *(const float4*)&Bs[kk][tx * 4];
            float ar[4] = {a4.x, a4.y, a4.z, a4.w};
            float br[4] = {b4.x, b4.y, b4.z, b4.w};
#pragma unroll
            for (int r = 0; r < 4; ++r)
#pragma unroll
                for (int c = 0; c < 4; ++c) acc[r][c] += ar[r] * br[c];
        }
        __syncthreads();
    }
#pragma unroll
    for (int r = 0; r < 4; ++r) {
        int row = bm + ty * 4 + r;
#pragma unroll
        for (int c = 0; c < 4; ++c) {
            int col = bn + tx * 4 + c;
            float v = acc[r][c] + bias[col];
            if (act == 1) v = fmaxf(v, 0.f);
            C[(long long)row * ldc + col] = v;
        }
    }
}

__global__ __launch_bounds__(256) void head2_k(const float* __restrict__ hh, const float* __restrict__ W2,
                                               const float* __restrict__ b2, float* __restrict__ out)
{
    int s = blockIdx.x * 256 + threadIdx.x;
    if (s >= SPX) return;
    float l0 = b2[0], l1 = b2[1];
    const float* hp = hh + (size_t)s * 128;
    for (int k = 0; k < 128; ++k) {
        float v = hp[k];
        l0 += v * W2[k * 2];
        l1 += v * W2[k * 2 + 1];
    }
    float m = fmaxf(l0, l1);
    float e0 = expf(l0 - m), e1 = expf(l1 - m);
    float inv = 1.f / (e0 + e1);
    out[s * 2] = e0 * inv;
    out[s * 2 + 1] = e1 * inv;
}

extern "C" void kernel_launch(void* const* d_in, const int* in_sizes, int n_in,
                              void* d_out, int out_size, void* d_ws, size_t ws_size,
                              hipStream_t stream)
{
    (void)in_sizes; (void)n_in; (void)out_size; (void)ws_size;
    const float* T1 = (const float*)d_in[0];
    const float* T2 = (const float*)d_in[1];
    const float* Abias = (const float*)d_in[3];
    const float* convW_in = (const float*)d_in[4];
    const float* convB_in = (const float*)d_in[5];
    const float* convW = (const float*)d_in[6];
    const float* convB = (const float*)d_in[7];
    const float* fc0_W = (const float*)d_in[8];
    const float* fc0_b = (const float*)d_in[9];
    const float* fc_W = (const float*)d_in[10];
    const float* fc_b = (const float*)d_in[11];
    const float* pos = (const float*)d_in[12];
    const float* ln1_g = (const float*)d_in[13];
    const float* ln1_b = (const float*)d_in[14];
    const float* qkv_W = (const float*)d_in[15];
    const float* out_W = (const float*)d_in[16];
    const float* out_b = (const float*)d_in[17];
    const float* ln2_g = (const float*)d_in[18];
    const float* ln2_b = (const float*)d_in[19];
    const float* ff_W1 = (const float*)d_in[20];
    const float* ff_b1 = (const float*)d_in[21];
    const float* ff_W2 = (const float*)d_in[22];
    const float* ff_b2 = (const float*)d_in[23];
    const float* head_W1 = (const float*)d_in[24];
    const float* head_b1 = (const float*)d_in[25];
    const float* head_W2 = (const float*)d_in[26];
    const float* head_b2 = (const float*)d_in[27];
    float* outp = (float*)d_out;

    char* wp = (char*)d_ws;
    auto alloc = [&](size_t bytes) { char* p = wp; wp += (bytes + 255) & ~(size_t)255; return p; };
    short* cbufA = (short*)alloc(16777216);
    short* cbufB = (short*)alloc(16777216);
    short* wt0   = (short*)alloc(2064384);
    short* wtl   = (short*)alloc(11796480);
    short* zbuf  = (short*)alloc(256);
    short* thwc  = (short*)alloc(14680064);
    short* qkvWT = (short*)alloc(9437184);
    short* outWT = (short*)alloc(3145728);
    short* ff1T  = (short*)alloc(3145728);
    short* ff2T  = (short*)alloc(3145728);
    short* fcT   = (short*)alloc(2621440);
    short* fc0WT = (short*)alloc(245760);
    short* qkvb  = (short*)alloc(6291456);
    short* obuf  = (short*)alloc(2097152);
    short* hbuf  = (short*)alloc(1048576);
    short* h2b   = (short*)alloc(1048576);
    short* ffhb  = (short*)alloc(2097152);
    short* catr  = (short*)alloc(2097152);
    float* LSb    = (float*)alloc(1835008);
    float* pooled = (float*)alloc(2097152);
    float* xinb   = (float*)alloc(2097152);
    float* xbuf   = (float*)alloc(2097152);
    float* dabs   = (float*)alloc(1048576);
    float* hhb    = (float*)alloc(524288);

    auto gemm = [&](const short* A, long long sA, int lda, const short* Bt, long long sB,
                    int N, int K, float* Cf, long long sCf, short* Cb, long long sCb, int ldc,
                    const float* bias, long long sBias, const float* addm, long long sAdd, int ldadd, int act) {
        gemm_bf16_k<<<dim3((unsigned)(N / 128), 8, 2), 256, 0, stream>>>(
            A, sA, lda, Bt, sB, K, Cf, sCf, Cb, sCb, ldc, bias, sBias, addm, sAdd, ldadd, act);
    };

    // ---- one-time preps (re-run every call; graph-safe) ----
    prep_weights_k<<<27072, 256, 0, stream>>>(convW_in, convW, wt0, wtl, zbuf);
    prep_thwc_k<<<28672, 256, 0, stream>>>(T1, T2, thwc);
    transpose_w_k<<<dim3(48, 8, 12), 256, 0, stream>>>(qkv_W, qkvWT, 256, 1536);
    transpose_w_k<<<dim3(8, 16, 12), 256, 0, stream>>>(out_W, outWT, 512, 256);
    transpose_w_k<<<dim3(16, 8, 12), 256, 0, stream>>>(ff_W1, ff1T, 256, 512);
    transpose_w_k<<<dim3(8, 16, 12), 256, 0, stream>>>(ff_W2, ff2T, 512, 256);
    transpose_w_k<<<dim3(8, 16, 10), 256, 0, stream>>>(fc_W, fcT, 512, 256);
    transpose_w_k<<<dim3(8, 15, 2), 256, 0, stream>>>(fc0_W, fc0WT, 480, 256);

    // LS = pooled raw inputs
    pool_bf16_k<<<dim3(896, 2), 256, 0, stream>>>(thwc, LSb, 224, 3670016LL, 229376LL);
    // conv layer 0 (224 -> 256)
    conv_mfma_k<<<dim3(2, 128, 2), 256, 0, stream>>>(thwc, 3670016LL, wt0, 516096LL, convB_in, 256LL,
                                                     cbufA, 4194304LL, zbuf, 224);
    short* cur = cbufA; short* nxt = cbufB;
    for (int s = 0; s < 6; ++s) {
        if (s > 0) {
            conv_mfma_k<<<dim3(2, 128, 2), 256, 0, stream>>>(cur, 4194304LL, wtl + (size_t)(s - 1) * 2 * 589824,
                                                             589824LL, convB + (size_t)(s - 1) * 512, 256LL,
                                                             nxt, 4194304LL, zbuf, 256);
            short* t = cur; cur = nxt; nxt = t;
        }
        pool_bf16_k<<<dim3(1024, 2), 256, 0, stream>>>(cur, pooled, 256, 4194304LL, 262144LL);
        if (s == 0) {
            concat_relu_k<<<dim3(1024, 2), 256, 0, stream>>>(pooled, 256, 262144LL, LSb, 224, 229376LL, catr, 491520LL);
            gemm(catr, 491520, 480, fc0WT, 122880, 256, 480, xinb, 262144, nullptr, 0, 256,
                 fc0_b, 256, nullptr, 0, 0, 0);
        } else {
            concat_relu_k<<<dim3(1024, 2), 256, 0, stream>>>(pooled, 256, 262144LL, xbuf, 256, 262144LL, catr, 524288LL);
            gemm(catr, 524288, 512, fcT + (size_t)(s - 1) * 262144, 131072, 256, 512, xinb, 262144,
                 nullptr, 0, 256, fc_b + (size_t)(s - 1) * 512, 256, nullptr, 0, 0, 0);
        }
        // encoder
        ln_k<<<dim3(1024, 2), 256, 0, stream>>>(xinb, pos + (size_t)s * 524288, xbuf,
                                                ln1_g + s * 512, ln1_b + s * 512, hbuf);
        gemm(hbuf, 262144, 256, qkvWT + (size_t)s * 786432, 393216, 1536, 256,
             nullptr, 0, qkvb, 1572864, 1536, nullptr, 0, nullptr, 0, 0, 0);
        flash_k<<<dim3(16, 8, 2), 256, 0, stream>>>(qkvb, Abias, obuf);
        gemm(obuf, 524288, 512, outWT + (size_t)s * 262144, 131072, 256, 512, xbuf, 262144,
             nullptr, 0, 256, out_b + s * 512, 256, xbuf, 262144, 256, 0);
        ln_k<<<dim3(1024, 2), 256, 0, stream>>>(xbuf, nullptr, nullptr,
                                                ln2_g + s * 512, ln2_b + s * 512, h2b);
        gemm(h2b, 262144, 256, ff1T + (size_t)s * 262144, 131072, 512, 256,
             nullptr, 0, ffhb, 524288, 512, ff_b1 + s * 1024, 512, nullptr, 0, 0, 2);
        gemm(ffhb, 524288, 512, ff2T + (size_t)s * 262144, 131072, 256, 512, xbuf, 262144,
             nullptr, 0, 256, ff_b2 + s * 512, 256, xbuf, 262144, 256, 0);
    }
    // head (fp32)
    absdiff_k<<<1024, 256, 0, stream>>>(xbuf, xbuf + 262144, dabs, 262144);
    gemm_f32_head<<<dim3(2, 16), 256, 0, stream>>>(dabs, head_W1, hhb, 256, 256, 128, 128, head_b1, 1);
    head2_k<<<4, 256, 0, stream>>>(hhb, head_W2, head_b2, outp);
}

// Round 4
// 1255.748 us; speedup vs baseline: 6.3649x; 1.4563x over previous
//
#include <hip/hip_runtime.h>
#include <hip/hip_bf16.h>
#include <math.h>

#define SPX 1024
#define HW 16384

typedef short short8 __attribute__((ext_vector_type(8)));
typedef short short4v __attribute__((ext_vector_type(4)));
typedef float f32x4 __attribute__((ext_vector_type(4)));

__device__ inline short f2bf(float v){ union{ __hip_bfloat16 h; short s; } u; u.h = __float2bfloat16(v); return u.s; }
__device__ inline float bf2f(short s){ union{ __hip_bfloat16 h; short t; } u; u.t = s; return __bfloat162float(u.h); }

// ---------------- conv weight prep -> bf16 [co][tap][ci]; zero pad-line ----------------
__global__ __launch_bounds__(256) void prep_weights_k(const float* __restrict__ cwin, const float* __restrict__ cw,
                                                      short* __restrict__ wt0, short* __restrict__ wtl,
                                                      short* __restrict__ zbuf)
{
    long long idx = (long long)blockIdx.x * 256 + threadIdx.x;
    if (idx < 64) zbuf[idx] = 0;
    const long long n0 = 2LL * 256 * 2016;
    if (idx < n0) {
        int br = (int)(idx / (256 * 2016)); int rem = (int)(idx % (256 * 2016));
        int co = rem / 2016; int k = rem % 2016;
        int tap = k / 224, ci = k % 224;
        wt0[idx] = f2bf(cwin[((size_t)(br * 256 + co) * 224 + ci) * 9 + tap]);
    } else {
        long long i2 = idx - n0;
        if (i2 < 10LL * 256 * 2304) {
            int l = (int)(i2 / (256 * 2304)); int rem = (int)(i2 % (256 * 2304));
            int co = rem / 2304; int k = rem % 2304;
            int tap = k / 256, ci = k % 256;
            wtl[i2] = f2bf(cw[((size_t)(l * 256 + co) * 256 + ci) * 9 + tap]);
        }
    }
}

// ---------------- T1/T2 CHW fp32 -> HWC bf16 ----------------
__global__ __launch_bounds__(256) void prep_thwc_k(const float* __restrict__ T1, const float* __restrict__ T2,
                                                   short* __restrict__ thwc)
{
    long long idx = (long long)blockIdx.x * 256 + threadIdx.x;
    int br = (int)(idx / 3670016LL); int rem = (int)(idx % 3670016LL);
    int p = rem / 224, c = rem % 224;
    const float* src = br ? T2 : T1;
    thwc[idx] = f2bf(src[(size_t)c * HW + p]);
}

// ---------------- generic fp32 [K][N] -> bf16 [N][K] transpose (32x32 LDS tiles) ----------------
__global__ __launch_bounds__(256) void transpose_w_k(const float* __restrict__ src, short* __restrict__ dst,
                                                     int K, int N)
{
    __shared__ float tile[32][33];
    int n0 = blockIdx.x * 32, k0 = blockIdx.y * 32, b = blockIdx.z;
    const float* s = src + (size_t)b * K * N;
    short* d = dst + (size_t)b * K * N;
    int tid = threadIdx.x;
    int r = tid >> 3, c4 = (tid & 7) * 4;
    float4 v = *(const float4*)(s + (size_t)(k0 + r) * N + n0 + c4);
    tile[r][c4 + 0] = v.x; tile[r][c4 + 1] = v.y; tile[r][c4 + 2] = v.z; tile[r][c4 + 3] = v.w;
    __syncthreads();
    short4v o;
#pragma unroll
    for (int i = 0; i < 4; ++i) o[i] = f2bf(tile[c4 + i][r]);
    *(short4v*)(d + (size_t)(n0 + r) * K + k0 + c4) = o;
}

// ---------------- fused implicit-GEMM 3x3 conv, bf16 MFMA, XCD-banded swizzle ----------------
// 1D grid of 512: xcd=id&7 -> {branch = xcd&1, 32-row y band = (xcd>>1)*32};
// t=id>>3 -> {y = band + (t>>1), co-half = (t&1)*128}. Keeps each XCD's working set
// (33 rows x 64KB + 1.2MB weights = 3.3MB) inside its 4MB L2.
__global__ __launch_bounds__(256) void conv_mfma_k(
    const short* __restrict__ inB, long long inStride,
    const short* __restrict__ wtB, long long wtStride,
    const float* __restrict__ biasB, long long biasStride,
    short* __restrict__ outB, long long outStride,
    const short* __restrict__ zbuf, int Cin)
{
    __shared__ short Asm[128 * 32];
    __shared__ short Bsm[128 * 32];
    int id = blockIdx.x;
    int x7 = id & 7, t = id >> 3;
    int br = x7 & 1;
    int y = (x7 >> 1) * 32 + (t >> 1);
    int co0 = (t & 1) * 128;
    const short* in = inB + (size_t)br * inStride;
    const short* wt = wtB + (size_t)br * wtStride;
    const float* bias = biasB + (size_t)br * biasStride;
    short* out = outB + (size_t)br * outStride;
    int tid = threadIdx.x;
    int lane = tid & 63, w = tid >> 6;
    int wm = w >> 1, wn = w & 1;
    int lrow = lane >> 2, lsub = (lane & 3) * 8;
    int Kw = 9 * Cin;
    f32x4 acc[4][4];
#pragma unroll
    for (int i = 0; i < 4; ++i)
#pragma unroll
        for (int j = 0; j < 4; ++j) acc[i][j] = (f32x4){0.f, 0.f, 0.f, 0.f};

    for (int tap = 0; tap < 9; ++tap) {
        int ky = tap / 3, kx = tap % 3;
        int gy = y + ky - 1;
        bool rowok = ((unsigned)gy < 128u);
        for (int c8 = 0; c8 < Cin; c8 += 32) {
#pragma unroll
            for (int s = 0; s < 2; ++s) {
                int r = w * 32 + s * 16 + lrow;
                int gx = r + kx - 1;
                const short* gp = (rowok && (unsigned)gx < 128u)
                    ? in + ((size_t)(gy * 128 + gx) * Cin + c8 + lsub)
                    : zbuf + lsub;
                __builtin_amdgcn_global_load_lds(
                    (const __attribute__((address_space(1))) void*)gp,
                    (__attribute__((address_space(3))) void*)(Asm + (w * 32 + s * 16) * 32),
                    16, 0, 0);
                const short* gq = wt + ((size_t)(co0 + r) * Kw + tap * Cin + c8 + lsub);
                __builtin_amdgcn_global_load_lds(
                    (const __attribute__((address_space(1))) void*)gq,
                    (__attribute__((address_space(3))) void*)(Bsm + (w * 32 + s * 16) * 32),
                    16, 0, 0);
            }
            __syncthreads();
            int mrow = lane & 15, kg = (lane >> 4) * 8;
            short8 af[4], bfr[4];
#pragma unroll
            for (int i = 0; i < 4; ++i)
                af[i] = *(const short8*)(Asm + (wm * 64 + i * 16 + mrow) * 32 + kg);
#pragma unroll
            for (int j = 0; j < 4; ++j)
                bfr[j] = *(const short8*)(Bsm + (wn * 64 + j * 16 + mrow) * 32 + kg);
#pragma unroll
            for (int i = 0; i < 4; ++i)
#pragma unroll
                for (int j = 0; j < 4; ++j)
                    acc[i][j] = __builtin_amdgcn_mfma_f32_16x16x32_bf16(af[i], bfr[j], acc[i][j], 0, 0, 0);
            __syncthreads();
        }
    }
    int ln15 = lane & 15, quad = lane >> 4;
    float bj[4];
#pragma unroll
    for (int j = 0; j < 4; ++j) bj[j] = bias[co0 + wn * 64 + j * 16 + ln15];
#pragma unroll
    for (int i = 0; i < 4; ++i) {
#pragma unroll
        for (int r = 0; r < 4; ++r) {
            int px = wm * 64 + i * 16 + quad * 4 + r;
            size_t po = ((size_t)y * 128 + px) * 256 + co0 + wn * 64 + ln15;
#pragma unroll
            for (int j = 0; j < 4; ++j)
                out[po + j * 16] = f2bf(acc[i][j][r] + bj[j]);
        }
    }
}

// ---------------- bf16 MFMA GEMM, 64x64 tile, BK=32 (small-shape / high-block-count) ----------------
// A: bf16 MxK (lda); Bt: bf16 NxK row-major. grid (N/64, M/64, Z)
__global__ __launch_bounds__(256) void gemm64_k(
    const short* __restrict__ A, long long sA, int lda,
    const short* __restrict__ Bt, long long sB, int K,
    float* Cf, long long sCf, short* Cb, long long sCb, int ldc,
    const float* __restrict__ bias, long long sBias,
    const float* addm, long long sAdd, int ldadd, int act)
{
    __shared__ short Asm[64 * 32];
    __shared__ short Bsm[64 * 32];
    int z = blockIdx.z;
    const short* Ap = A + (size_t)z * sA;
    const short* Bp = Bt + (size_t)z * sB;
    const float* biasp = bias ? bias + (size_t)z * sBias : nullptr;
    const float* addp = addm ? addm + (size_t)z * sAdd : nullptr;
    int bn = blockIdx.x * 64, bm = blockIdx.y * 64;
    int tid = threadIdx.x;
    int lane = tid & 63, w = tid >> 6;
    int wm = w >> 1, wn = w & 1;
    int rr = tid >> 2, lsub = (tid & 3) * 8;
    f32x4 acc[2][2];
#pragma unroll
    for (int i = 0; i < 2; ++i)
#pragma unroll
        for (int j = 0; j < 2; ++j) acc[i][j] = (f32x4){0.f, 0.f, 0.f, 0.f};

    for (int k0 = 0; k0 < K; k0 += 32) {
        const short* gp = Ap + (size_t)(bm + rr) * lda + k0 + lsub;
        __builtin_amdgcn_global_load_lds(
            (const __attribute__((address_space(1))) void*)gp,
            (__attribute__((address_space(3))) void*)(Asm + (w * 16) * 32), 16, 0, 0);
        const short* gq = Bp + (size_t)(bn + rr) * K + k0 + lsub;
        __builtin_amdgcn_global_load_lds(
            (const __attribute__((address_space(1))) void*)gq,
            (__attribute__((address_space(3))) void*)(Bsm + (w * 16) * 32), 16, 0, 0);
        __syncthreads();
        int mrow = lane & 15, kg = (lane >> 4) * 8;
        short8 af[2], bfr[2];
#pragma unroll
        for (int i = 0; i < 2; ++i)
            af[i] = *(const short8*)(Asm + (wm * 32 + i * 16 + mrow) * 32 + kg);
#pragma unroll
        for (int j = 0; j < 2; ++j)
            bfr[j] = *(const short8*)(Bsm + (wn * 32 + j * 16 + mrow) * 32 + kg);
#pragma unroll
        for (int i = 0; i < 2; ++i)
#pragma unroll
            for (int j = 0; j < 2; ++j)
                acc[i][j] = __builtin_amdgcn_mfma_f32_16x16x32_bf16(af[i], bfr[j], acc[i][j], 0, 0, 0);
        __syncthreads();
    }
    int ln15 = lane & 15, quad = lane >> 4;
    float* Cfp = Cf ? Cf + (size_t)z * sCf : nullptr;
    short* Cbp = Cb ? Cb + (size_t)z * sCb : nullptr;
#pragma unroll
    for (int i = 0; i < 2; ++i) {
#pragma unroll
        for (int r = 0; r < 4; ++r) {
            int row = bm + wm * 32 + i * 16 + quad * 4 + r;
            long long ro = (long long)row * ldc;
#pragma unroll
            for (int j = 0; j < 2; ++j) {
                int col = bn + wn * 32 + j * 16 + ln15;
                float v = acc[i][j][r];
                if (biasp) v += biasp[col];
                if (addp) v += addp[(long long)row * ldadd + col];
                if (act == 1) v = fmaxf(v, 0.f);
                else if (act == 2) v = 0.5f * v * (1.f + erff(v * 0.70710678118f));
                if (Cfp) Cfp[ro + col] = v;
                if (Cbp) Cbp[ro + col] = f2bf(v);
            }
        }
    }
}

// ---------------- fused flash attention: per block (64 Q-rows, head, branch) ----------------
__global__ __launch_bounds__(256) void flash_k(const short* __restrict__ qkv, const float* __restrict__ Abias,
                                               short* __restrict__ obuf)
{
    __shared__ short Qs[64 * 72];
    __shared__ short Ks[128 * 72];
    __shared__ short Vt[64 * 136];
    __shared__ short Ps[64 * 136];
    int q0 = blockIdx.x * 64, h = blockIdx.y, br = blockIdx.z;
    const short* qb = qkv + (size_t)br * 1572864;
    int tid = threadIdx.x;
    int lane = tid & 63, w = tid >> 6;
    int ln15 = lane & 15, quad = lane >> 4;
    {
        int row = tid & 63, c0 = (tid >> 6) * 16;
        const short* src = qb + (size_t)(q0 + row) * 1536 + h * 64 + c0;
        *(short8*)(Qs + row * 72 + c0) = *(const short8*)src;
        *(short8*)(Qs + row * 72 + c0 + 8) = *(const short8*)(src + 8);
    }
    f32x4 Oc[4];
    float mrow[4], lsum[4];
#pragma unroll
    for (int i = 0; i < 4; ++i) { Oc[i] = (f32x4){0.f, 0.f, 0.f, 0.f}; mrow[i] = -1e30f; lsum[i] = 0.f; }

    for (int j = 0; j < 8; ++j) {
        int k0 = j * 128;
        {
            int row = tid & 127, half = tid >> 7;
            const short* ks = qb + (size_t)(k0 + row) * 1536 + 512 + h * 64 + half * 32;
#pragma unroll
            for (int g = 0; g < 4; ++g)
                *(short8*)(Ks + row * 72 + half * 32 + g * 8) = *(const short8*)(ks + g * 8);
            const short* vs = qb + (size_t)(k0 + row) * 1536 + 1024 + h * 64 + half * 32;
#pragma unroll
            for (int g = 0; g < 4; ++g) {
                short8 vv = *(const short8*)(vs + g * 8);
#pragma unroll
                for (int e = 0; e < 8; ++e)
                    Vt[(half * 32 + g * 8 + e) * 136 + row] = vv[e];
            }
        }
        __syncthreads();
        short8 aq[2];
#pragma unroll
        for (int g = 0; g < 2; ++g)
            aq[g] = *(const short8*)(Qs + (w * 16 + ln15) * 72 + g * 32 + quad * 8);
        f32x4 Sf[8];
#pragma unroll
        for (int nf = 0; nf < 8; ++nf) Sf[nf] = (f32x4){0.f, 0.f, 0.f, 0.f};
#pragma unroll
        for (int nf = 0; nf < 8; ++nf)
#pragma unroll
            for (int g = 0; g < 2; ++g) {
                short8 bk = *(const short8*)(Ks + (nf * 16 + ln15) * 72 + g * 32 + quad * 8);
                Sf[nf] = __builtin_amdgcn_mfma_f32_16x16x32_bf16(aq[g], bk, Sf[nf], 0, 0, 0);
            }
        float rm[4] = {-1e30f, -1e30f, -1e30f, -1e30f};
#pragma unroll
        for (int nf = 0; nf < 8; ++nf)
#pragma unroll
            for (int r = 0; r < 4; ++r) {
                float v = Sf[nf][r] * 0.125f +
                          Abias[(size_t)(q0 + w * 16 + quad * 4 + r) * 1024 + k0 + nf * 16 + ln15];
                Sf[nf][r] = v;
                rm[r] = fmaxf(rm[r], v);
            }
#pragma unroll
        for (int r = 0; r < 4; ++r)
#pragma unroll
            for (int msk = 1; msk < 16; msk <<= 1)
                rm[r] = fmaxf(rm[r], __shfl_xor(rm[r], msk));
        float alpha[4], rs[4];
#pragma unroll
        for (int r = 0; r < 4; ++r) {
            float mnew = fmaxf(mrow[r], rm[r]);
            alpha[r] = __expf(mrow[r] - mnew);
            mrow[r] = mnew;
            rs[r] = 0.f;
        }
#pragma unroll
        for (int nf = 0; nf < 8; ++nf)
#pragma unroll
            for (int r = 0; r < 4; ++r) {
                float p = __expf(Sf[nf][r] - mrow[r]);
                Sf[nf][r] = p;
                rs[r] += p;
            }
#pragma unroll
        for (int r = 0; r < 4; ++r) {
#pragma unroll
            for (int msk = 1; msk < 16; msk <<= 1)
                rs[r] += __shfl_xor(rs[r], msk);
            lsum[r] = lsum[r] * alpha[r] + rs[r];
        }
#pragma unroll
        for (int nf = 0; nf < 4; ++nf)
#pragma unroll
            for (int r = 0; r < 4; ++r) Oc[nf][r] *= alpha[r];
#pragma unroll
        for (int nf = 0; nf < 8; ++nf)
#pragma unroll
            for (int r = 0; r < 4; ++r)
                Ps[(w * 16 + quad * 4 + r) * 136 + nf * 16 + ln15] = f2bf(Sf[nf][r]);
        __syncthreads();
#pragma unroll
        for (int g = 0; g < 4; ++g) {
            short8 ap = *(const short8*)(Ps + (w * 16 + ln15) * 136 + g * 32 + quad * 8);
#pragma unroll
            for (int nf = 0; nf < 4; ++nf) {
                short8 bv = *(const short8*)(Vt + (nf * 16 + ln15) * 136 + g * 32 + quad * 8);
                Oc[nf] = __builtin_amdgcn_mfma_f32_16x16x32_bf16(ap, bv, Oc[nf], 0, 0, 0);
            }
        }
        __syncthreads();
    }
#pragma unroll
    for (int nf = 0; nf < 4; ++nf)
#pragma unroll
        for (int r = 0; r < 4; ++r) {
            int row = q0 + w * 16 + quad * 4 + r;
            obuf[(size_t)br * 524288 + (size_t)row * 512 + h * 64 + nf * 16 + ln15] =
                f2bf(Oc[nf][r] / lsum[r]);
        }
}

// ---------------- superpixel mean pooling from bf16 HWC ----------------
__global__ __launch_bounds__(256) void pool_bf16_k(const short* __restrict__ in, float* __restrict__ out,
                                                   int C, long long inZ, long long outZ)
{
    int z = blockIdx.y;
    int tid = blockIdx.x * 256 + threadIdx.x;
    int s = tid / C, c = tid - s * C;
    const short* p = in + (size_t)z * inZ + (size_t)s * C + c;
    float acc = 0.f;
#pragma unroll
    for (int j = 0; j < 16; ++j) acc += bf2f(p[(size_t)j * 1024 * C]);
    out[(size_t)z * outZ + (size_t)s * C + c] = acc * (1.f / 16.f);
}

// ---------------- layernorm over 256: one wave per row, shfl reductions ----------------
__global__ __launch_bounds__(256) void ln_k(const float* __restrict__ xin, const float* __restrict__ pos,
                                            float* __restrict__ xout, const float* __restrict__ g,
                                            const float* __restrict__ b, short* __restrict__ hout)
{
    int w = threadIdx.x >> 6, lane = threadIdx.x & 63;
    int row = blockIdx.x * 4 + w, z = blockIdx.y;
    size_t o = (size_t)z * 262144 + (size_t)row * 256 + lane * 4;
    float4 v = *(const float4*)(xin + o);
    if (pos) {
        float4 p = *(const float4*)(pos + o);
        v.x += p.x; v.y += p.y; v.z += p.z; v.w += p.w;
    }
    if (xout) *(float4*)(xout + o) = v;
    float s = v.x + v.y + v.z + v.w;
#pragma unroll
    for (int msk = 1; msk < 64; msk <<= 1) s += __shfl_xor(s, msk);
    float m = s * (1.f / 256.f);
    float d0 = v.x - m, d1 = v.y - m, d2 = v.z - m, d3 = v.w - m;
    float q = d0 * d0 + d1 * d1 + d2 * d2 + d3 * d3;
#pragma unroll
    for (int msk = 1; msk < 64; msk <<= 1) q += __shfl_xor(q, msk);
    float rs = rsqrtf(q * (1.f / 256.f) + 1e-5f);
    const float* gp = g + z * 256 + lane * 4;
    const float* bp = b + z * 256 + lane * 4;
    short4v hv;
    hv[0] = f2bf(d0 * rs * gp[0] + bp[0]);
    hv[1] = f2bf(d1 * rs * gp[1] + bp[1]);
    hv[2] = f2bf(d2 * rs * gp[2] + bp[2]);
    hv[3] = f2bf(d3 * rs * gp[3] + bp[3]);
    *(short4v*)(hout + o) = hv;
}

// ---------------- concat + relu -> bf16 ----------------
__global__ __launch_bounds__(256) void concat_relu_k(const float* __restrict__ a, int ca, long long aZ,
                                                     const float* __restrict__ b, int cb, long long bZ,
                                                     short* __restrict__ out, long long oZ)
{
    int row = blockIdx.x, z = blockIdx.y;
    int n = ca + cb;
    const float* ap = a + (size_t)z * aZ + (size_t)row * ca;
    const float* bp = b + (size_t)z * bZ + (size_t)row * cb;
    short* op = out + (size_t)z * oZ + (size_t)row * n;
    for (int col = threadIdx.x; col < n; col += 256) {
        float v = (col < ca) ? ap[col] : bp[col - ca];
        op[col] = f2bf(fmaxf(v, 0.f));
    }
}

__global__ __launch_bounds__(256) void absdiff_k(const float* __restrict__ a, const float* __restrict__ b,
                                                 float* __restrict__ o, int n)
{
    int i = blockIdx.x * 256 + threadIdx.x;
    if (i < n) o[i] = fabsf(a[i] - b[i]);
}

// ---------------- fp32 head GEMM (64x64 tiles) ----------------
__global__ __launch_bounds__(256) void gemm_f32_head(const float* __restrict__ A, const float* __restrict__ B,
                                                     float* __restrict__ C, int K, int lda, int ldb, int ldc,
                                                     const float* __restrict__ bias, int act)
{
    __shared__ __align__(16) float As[16][68];
    __shared__ __align__(16) float Bs[16][68];
    int bn = blockIdx.x * 64, bm = blockIdx.y * 64;
    int tid = threadIdx.x;
    int tx = tid & 15, ty = tid >> 4;
    float acc[4][4];
#pragma unroll
    for (int r = 0; r < 4; ++r)
#pragma unroll
        for (int c = 0; c < 4; ++c) acc[r][c] = 0.f;
    int mmA = tid >> 2, kqA = (tid & 3) * 4;
    int kkB = tid >> 4, nqB = (tid & 15) * 4;
    for (int k0 = 0; k0 < K; k0 += 16) {
        float4 av = *(const float4*)(A + (long long)(bm + mmA) * lda + k0 + kqA);
        As[kqA + 0][mmA] = av.x; As[kqA + 1][mmA] = av.y;
        As[kqA + 2][mmA] = av.z; As[kqA + 3][mmA] = av.w;
        *(float4*)&Bs[kkB][nqB] = *(const float4*)(B + (long long)(k0 + kkB) * ldb + bn + nqB);
        __syncthreads();
#pragma unroll
        for (int kk = 0; kk < 16; ++kk) {
            float4 a4 = *(const float4*)&As[kk][ty * 4];
            float4 b4 = *(const float4*)&Bs[kk][tx * 4];
            float ar[4] = {a4.x, a4.y, a4.z, a4.w};
            float br[4] = {b4.x, b4.y, b4.z, b4.w};
#pragma unroll
            for (int r = 0; r < 4; ++r)
#pragma unroll
                for (int c = 0; c < 4; ++c) acc[r][c] += ar[r] * br[c];
        }
        __syncthreads();
    }
#pragma unroll
    for (int r = 0; r < 4; ++r) {
        int row = bm + ty * 4 + r;
#pragma unroll
        for (int c = 0; c < 4; ++c) {
            int col = bn + tx * 4 + c;
            float v = acc[r][c] + bias[col];
            if (act == 1) v = fmaxf(v, 0.f);
            C[(long long)row * ldc + col] = v;
        }
    }
}

__global__ __launch_bounds__(256) void head2_k(const float* __restrict__ hh, const float* __restrict__ W2,
                                               const float* __restrict__ b2, float* __restrict__ out)
{
    int s = blockIdx.x * 256 + threadIdx.x;
    if (s >= SPX) return;
    float l0 = b2[0], l1 = b2[1];
    const float* hp = hh + (size_t)s * 128;
    for (int k = 0; k < 128; ++k) {
        float v = hp[k];
        l0 += v * W2[k * 2];
        l1 += v * W2[k * 2 + 1];
    }
    float m = fmaxf(l0, l1);
    float e0 = __expf(l0 - m), e1 = __expf(l1 - m);
    float inv = 1.f / (e0 + e1);
    out[s * 2] = e0 * inv;
    out[s * 2 + 1] = e1 * inv;
}

extern "C" void kernel_launch(void* const* d_in, const int* in_sizes, int n_in,
                              void* d_out, int out_size, void* d_ws, size_t ws_size,
                              hipStream_t stream)
{
    (void)in_sizes; (void)n_in; (void)out_size; (void)ws_size;
    const float* T1 = (const float*)d_in[0];
    const float* T2 = (const float*)d_in[1];
    const float* Abias = (const float*)d_in[3];
    const float* convW_in = (const float*)d_in[4];
    const float* convB_in = (const float*)d_in[5];
    const float* convW = (const float*)d_in[6];
    const float* convB = (const float*)d_in[7];
    const float* fc0_W = (const float*)d_in[8];
    const float* fc0_b = (const float*)d_in[9];
    const float* fc_W = (const float*)d_in[10];
    const float* fc_b = (const float*)d_in[11];
    const float* pos = (const float*)d_in[12];
    const float* ln1_g = (const float*)d_in[13];
    const float* ln1_b = (const float*)d_in[14];
    const float* qkv_W = (const float*)d_in[15];
    const float* out_W = (const float*)d_in[16];
    const float* out_b = (const float*)d_in[17];
    const float* ln2_g = (const float*)d_in[18];
    const float* ln2_b = (const float*)d_in[19];
    const float* ff_W1 = (const float*)d_in[20];
    const float* ff_b1 = (const float*)d_in[21];
    const float* ff_W2 = (const float*)d_in[22];
    const float* ff_b2 = (const float*)d_in[23];
    const float* head_W1 = (const float*)d_in[24];
    const float* head_b1 = (const float*)d_in[25];
    const float* head_W2 = (const float*)d_in[26];
    const float* head_b2 = (const float*)d_in[27];
    float* outp = (float*)d_out;

    char* wp = (char*)d_ws;
    auto alloc = [&](size_t bytes) { char* p = wp; wp += (bytes + 255) & ~(size_t)255; return p; };
    short* cbufA = (short*)alloc(16777216);
    short* cbufB = (short*)alloc(16777216);
    short* wt0   = (short*)alloc(2064384);
    short* wtl   = (short*)alloc(11796480);
    short* zbuf  = (short*)alloc(256);
    short* thwc  = (short*)alloc(14680064);
    short* qkvWT = (short*)alloc(9437184);
    short* outWT = (short*)alloc(3145728);
    short* ff1T  = (short*)alloc(3145728);
    short* ff2T  = (short*)alloc(3145728);
    short* fcT   = (short*)alloc(2621440);
    short* fc0WT = (short*)alloc(245760);
    short* qkvb  = (short*)alloc(6291456);
    short* obuf  = (short*)alloc(2097152);
    short* hbuf  = (short*)alloc(1048576);
    short* h2b   = (short*)alloc(1048576);
    short* ffhb  = (short*)alloc(2097152);
    short* catr  = (short*)alloc(2097152);
    float* LSb    = (float*)alloc(1835008);
    float* pooled = (float*)alloc(2097152);
    float* xinb   = (float*)alloc(2097152);
    float* xbuf   = (float*)alloc(2097152);
    float* dabs   = (float*)alloc(1048576);
    float* hhb    = (float*)alloc(524288);

    auto gemm = [&](const short* A, long long sA, int lda, const short* Bt, long long sB,
                    int N, int K, float* Cf, long long sCf, short* Cb, long long sCb, int ldc,
                    const float* bias, long long sBias, const float* addm, long long sAdd, int ldadd, int act) {
        gemm64_k<<<dim3((unsigned)(N / 64), 16, 2), 256, 0, stream>>>(
            A, sA, lda, Bt, sB, K, Cf, sCf, Cb, sCb, ldc, bias, sBias, addm, sAdd, ldadd, act);
    };

    // ---- one-time preps (re-run every call; graph-safe) ----
    prep_weights_k<<<27072, 256, 0, stream>>>(convW_in, convW, wt0, wtl, zbuf);
    prep_thwc_k<<<28672, 256, 0, stream>>>(T1, T2, thwc);
    transpose_w_k<<<dim3(48, 8, 12), 256, 0, stream>>>(qkv_W, qkvWT, 256, 1536);
    transpose_w_k<<<dim3(8, 16, 12), 256, 0, stream>>>(out_W, outWT, 512, 256);
    transpose_w_k<<<dim3(16, 8, 12), 256, 0, stream>>>(ff_W1, ff1T, 256, 512);
    transpose_w_k<<<dim3(8, 16, 12), 256, 0, stream>>>(ff_W2, ff2T, 512, 256);
    transpose_w_k<<<dim3(8, 16, 10), 256, 0, stream>>>(fc_W, fcT, 512, 256);
    transpose_w_k<<<dim3(8, 15, 2), 256, 0, stream>>>(fc0_W, fc0WT, 480, 256);

    // LS = pooled raw inputs
    pool_bf16_k<<<dim3(896, 2), 256, 0, stream>>>(thwc, LSb, 224, 3670016LL, 229376LL);
    // conv layer 0 (224 -> 256)
    conv_mfma_k<<<512, 256, 0, stream>>>(thwc, 3670016LL, wt0, 516096LL, convB_in, 256LL,
                                         cbufA, 4194304LL, zbuf, 224);
    short* cur = cbufA; short* nxt = cbufB;
    for (int s = 0; s < 6; ++s) {
        if (s > 0) {
            conv_mfma_k<<<512, 256, 0, stream>>>(cur, 4194304LL, wtl + (size_t)(s - 1) * 2 * 589824,
                                                 589824LL, convB + (size_t)(s - 1) * 512, 256LL,
                                                 nxt, 4194304LL, zbuf, 256);
            short* t = cur; cur = nxt; nxt = t;
        }
        pool_bf16_k<<<dim3(1024, 2), 256, 0, stream>>>(cur, pooled, 256, 4194304LL, 262144LL);
        if (s == 0) {
            concat_relu_k<<<dim3(1024, 2), 256, 0, stream>>>(pooled, 256, 262144LL, LSb, 224, 229376LL, catr, 491520LL);
            gemm(catr, 491520, 480, fc0WT, 122880, 256, 480, xinb, 262144, nullptr, 0, 256,
                 fc0_b, 256, nullptr, 0, 0, 0);
        } else {
            concat_relu_k<<<dim3(1024, 2), 256, 0, stream>>>(pooled, 256, 262144LL, xbuf, 256, 262144LL, catr, 524288LL);
            gemm(catr, 524288, 512, fcT + (size_t)(s - 1) * 262144, 131072, 256, 512, xinb, 262144,
                 nullptr, 0, 256, fc_b + (size_t)(s - 1) * 512, 256, nullptr, 0, 0, 0);
        }
        // encoder
        ln_k<<<dim3(256, 2), 256, 0, stream>>>(xinb, pos + (size_t)s * 524288, xbuf,
                                               ln1_g + s * 512, ln1_b + s * 512, hbuf);
        gemm(hbuf, 262144, 256, qkvWT + (size_t)s * 786432, 393216, 1536, 256,
             nullptr, 0, qkvb, 1572864, 1536, nullptr, 0, nullptr, 0, 0, 0);
        flash_k<<<dim3(16, 8, 2), 256, 0, stream>>>(qkvb, Abias, obuf);
        gemm(obuf, 524288, 512, outWT + (size_t)s * 262144, 131072, 256, 512, xbuf, 262144,
             nullptr, 0, 256, out_b + s * 512, 256, xbuf, 262144, 256, 0);
        ln_k<<<dim3(256, 2), 256, 0, stream>>>(xbuf, nullptr, nullptr,
                                               ln2_g + s * 512, ln2_b + s * 512, h2b);
        gemm(h2b, 262144, 256, ff1T + (size_t)s * 262144, 131072, 512, 256,
             nullptr, 0, ffhb, 524288, 512, ff_b1 + s * 1024, 512, nullptr, 0, 0, 2);
        gemm(ffhb, 524288, 512, ff2T + (size_t)s * 262144, 131072, 256, 512, xbuf, 262144,
             nullptr, 0, 256, ff_b2 + s * 512, 256, xbuf, 262144, 256, 0);
    }
    // head (fp32)
    absdiff_k<<<1024, 256, 0, stream>>>(xbuf, xbuf + 262144, dabs, 262144);
    gemm_f32_head<<<dim3(2, 16), 256, 0, stream>>>(dabs, head_W1, hhb, 256, 256, 128, 128, head_b1, 1);
    head2_k<<<4, 256, 0, stream>>>(hhb, head_W2, head_b2, outp);
}

// Round 5
// 1160.879 us; speedup vs baseline: 6.8851x; 1.0817x over previous
//
#include <hip/hip_runtime.h>
#include <hip/hip_bf16.h>
#include <math.h>

#define SPX 1024
#define HW 16384

typedef short short8 __attribute__((ext_vector_type(8)));
typedef short short4v __attribute__((ext_vector_type(4)));
typedef float f32x4 __attribute__((ext_vector_type(4)));

__device__ inline short f2bf(float v){ union{ __hip_bfloat16 h; short s; } u; u.h = __float2bfloat16(v); return u.s; }
__device__ inline float bf2f(short s){ union{ __hip_bfloat16 h; short t; } u; u.t = s; return __bfloat162float(u.h); }

#define GLL(gp, lp) __builtin_amdgcn_global_load_lds( \
    (const __attribute__((address_space(1))) void*)(gp), \
    (__attribute__((address_space(3))) void*)(lp), 16, 0, 0)

// ---------------- conv weight prep -> bf16 [co][tap][ci]; zero pad-line ----------------
__global__ __launch_bounds__(256) void prep_weights_k(const float* __restrict__ cwin, const float* __restrict__ cw,
                                                      short* __restrict__ wt0, short* __restrict__ wtl,
                                                      short* __restrict__ zbuf)
{
    long long idx = (long long)blockIdx.x * 256 + threadIdx.x;
    if (idx < 64) zbuf[idx] = 0;
    const long long n0 = 2LL * 256 * 2016;
    if (idx < n0) {
        int br = (int)(idx / (256 * 2016)); int rem = (int)(idx % (256 * 2016));
        int co = rem / 2016; int k = rem % 2016;
        int tap = k / 224, ci = k % 224;
        wt0[idx] = f2bf(cwin[((size_t)(br * 256 + co) * 224 + ci) * 9 + tap]);
    } else {
        long long i2 = idx - n0;
        if (i2 < 10LL * 256 * 2304) {
            int l = (int)(i2 / (256 * 2304)); int rem = (int)(i2 % (256 * 2304));
            int co = rem / 2304; int k = rem % 2304;
            int tap = k / 256, ci = k % 256;
            wtl[i2] = f2bf(cw[((size_t)(l * 256 + co) * 256 + ci) * 9 + tap]);
        }
    }
}

// ---------------- T1/T2 CHW fp32 -> HWC bf16 ----------------
__global__ __launch_bounds__(256) void prep_thwc_k(const float* __restrict__ T1, const float* __restrict__ T2,
                                                   short* __restrict__ thwc)
{
    long long idx = (long long)blockIdx.x * 256 + threadIdx.x;
    int br = (int)(idx / 3670016LL); int rem = (int)(idx % 3670016LL);
    int p = rem / 224, c = rem % 224;
    const float* src = br ? T2 : T1;
    thwc[idx] = f2bf(src[(size_t)c * HW + p]);
}

// ---------------- generic fp32 [K][N] -> bf16 [N][K] transpose (32x32 LDS tiles) ----------------
__global__ __launch_bounds__(256) void transpose_w_k(const float* __restrict__ src, short* __restrict__ dst,
                                                     int K, int N)
{
    __shared__ float tile[32][33];
    int n0 = blockIdx.x * 32, k0 = blockIdx.y * 32, b = blockIdx.z;
    const float* s = src + (size_t)b * K * N;
    short* d = dst + (size_t)b * K * N;
    int tid = threadIdx.x;
    int r = tid >> 3, c4 = (tid & 7) * 4;
    float4 v = *(const float4*)(s + (size_t)(k0 + r) * N + n0 + c4);
    tile[r][c4 + 0] = v.x; tile[r][c4 + 1] = v.y; tile[r][c4 + 2] = v.z; tile[r][c4 + 3] = v.w;
    __syncthreads();
    short4v o;
#pragma unroll
    for (int i = 0; i < 4; ++i) o[i] = f2bf(tile[c4 + i][r]);
    *(short4v*)(d + (size_t)(n0 + r) * K + k0 + c4) = o;
}

// ---------------- fused implicit-GEMM 3x3 conv v3: halo-A staging + B double-buffer ----------------
// 1D grid 512, XCD-banded. Block: y row, 128 px x 128 co. Per 32-ci chunk: stage 3x130-px halo A once,
// loop 9 taps reading kx-shifted LDS rows; B tile double-buffered (staged during prior tap's MFMA).
__global__ __launch_bounds__(256) void conv_mfma_k(
    const short* __restrict__ inB, long long inStride,
    const short* __restrict__ wtB, long long wtStride,
    const float* __restrict__ biasB, long long biasStride,
    short* __restrict__ outB, long long outStride,
    const short* __restrict__ zbuf, int Cin)
{
    __shared__ short Ah[3 * 4160];    // 3 dy x 130 rows x 32 ci (rows 0 and 129 are zero guards)
    __shared__ short Bs[2][4096];     // double-buffered 128 co x 32 ci
    int id = blockIdx.x;
    int x7 = id & 7, t = id >> 3;
    int br = x7 & 1;
    int y = (x7 >> 1) * 32 + (t >> 1);
    int co0 = (t & 1) * 128;
    const short* in = inB + (size_t)br * inStride;
    const short* wt = wtB + (size_t)br * wtStride;
    const float* bias = biasB + (size_t)br * biasStride;
    short* out = outB + (size_t)br * outStride;
    int tid = threadIdx.x;
    int lane = tid & 63, w = tid >> 6;
    int wm = w >> 1, wn = w & 1;
    int lrow = lane >> 2, lsub = (lane & 3) * 8;
    int Kw = 9 * Cin;
    // zero halo guard rows
    if (tid < 96) {
        int dy = tid >> 5, ci = tid & 31;
        Ah[dy * 4160 + ci] = 0;
        Ah[dy * 4160 + 129 * 32 + ci] = 0;
    }
    f32x4 acc[4][4];
#pragma unroll
    for (int i = 0; i < 4; ++i)
#pragma unroll
        for (int j = 0; j < 4; ++j) acc[i][j] = (f32x4){0.f, 0.f, 0.f, 0.f};

    auto stageA = [&](int cc) {
        int c8 = cc * 32;
#pragma unroll
        for (int g = 0; g < 6; ++g) {
            int idg = g * 4 + w;
            int dy = idg >> 3, grp = idg & 7;
            int gy = y + dy - 1;
            const short* gp = ((unsigned)gy < 128u)
                ? in + ((size_t)(gy * 128 + grp * 16 + lrow) * Cin + c8 + lsub)
                : zbuf + lsub;
            GLL(gp, Ah + dy * 4160 + (1 + grp * 16) * 32);
        }
    };
    auto stageB = [&](int cc, int tap, int p) {
        int c8 = cc * 32;
#pragma unroll
        for (int s = 0; s < 2; ++s) {
            int r0 = (s * 4 + w) * 16;
            const short* gq = wt + ((size_t)(co0 + r0 + lrow) * Kw + tap * Cin + c8 + lsub);
            GLL(gq, Bs[p] + r0 * 32);
        }
    };

    stageA(0);
    stageB(0, 0, 0);
    __syncthreads();
    int NC = Cin >> 5;
    int pb = 0;
    int mrow = lane & 15, kg = (lane >> 4) * 8;
    for (int cc = 0; cc < NC; ++cc) {
#pragma unroll
        for (int tap = 0; tap < 9; ++tap) {
            if (tap < 8) stageB(cc, tap + 1, pb ^ 1);
            else if (cc + 1 < NC) stageB(cc + 1, 0, pb ^ 1);
            int ky = tap / 3, kx = tap % 3;
            const short* Ap = Ah + ky * 4160 + kx * 32;
            short8 af[4], bfr[4];
#pragma unroll
            for (int i = 0; i < 4; ++i)
                af[i] = *(const short8*)(Ap + (wm * 64 + i * 16 + mrow) * 32 + kg);
#pragma unroll
            for (int j = 0; j < 4; ++j)
                bfr[j] = *(const short8*)(Bs[pb] + (wn * 64 + j * 16 + mrow) * 32 + kg);
#pragma unroll
            for (int i = 0; i < 4; ++i)
#pragma unroll
                for (int j = 0; j < 4; ++j)
                    acc[i][j] = __builtin_amdgcn_mfma_f32_16x16x32_bf16(af[i], bfr[j], acc[i][j], 0, 0, 0);
            __syncthreads();
            pb ^= 1;
        }
        if (cc + 1 < NC) {
            stageA(cc + 1);
            __syncthreads();
        }
    }
    int ln15 = lane & 15, quad = lane >> 4;
    float bj[4];
#pragma unroll
    for (int j = 0; j < 4; ++j) bj[j] = bias[co0 + wn * 64 + j * 16 + ln15];
#pragma unroll
    for (int i = 0; i < 4; ++i) {
#pragma unroll
        for (int r = 0; r < 4; ++r) {
            int px = wm * 64 + i * 16 + quad * 4 + r;
            size_t po = ((size_t)y * 128 + px) * 256 + co0 + wn * 64 + ln15;
#pragma unroll
            for (int j = 0; j < 4; ++j)
                out[po + j * 16] = f2bf(acc[i][j][r] + bj[j]);
        }
    }
}

// ---------------- bf16 MFMA GEMM, 64x64 tile, BK=32, double-buffered ----------------
__global__ __launch_bounds__(256) void gemm64_k(
    const short* __restrict__ A, long long sA, int lda,
    const short* __restrict__ Bt, long long sB, int K,
    float* Cf, long long sCf, short* Cb, long long sCb, int ldc,
    const float* __restrict__ bias, long long sBias,
    const float* addm, long long sAdd, int ldadd, int act)
{
    __shared__ short Asm[2][2048];
    __shared__ short Bsm[2][2048];
    int z = blockIdx.z;
    const short* Ap = A + (size_t)z * sA;
    const short* Bp = Bt + (size_t)z * sB;
    const float* biasp = bias ? bias + (size_t)z * sBias : nullptr;
    const float* addp = addm ? addm + (size_t)z * sAdd : nullptr;
    int bn = blockIdx.x * 64, bm = blockIdx.y * 64;
    int tid = threadIdx.x;
    int lane = tid & 63, w = tid >> 6;
    int wm = w >> 1, wn = w & 1;
    int rr = tid >> 2, lsub = (tid & 3) * 8;
    f32x4 acc[2][2];
#pragma unroll
    for (int i = 0; i < 2; ++i)
#pragma unroll
        for (int j = 0; j < 2; ++j) acc[i][j] = (f32x4){0.f, 0.f, 0.f, 0.f};

    auto stage = [&](int k0, int p) {
        GLL(Ap + (size_t)(bm + rr) * lda + k0 + lsub, Asm[p] + (w * 16) * 32);
        GLL(Bp + (size_t)(bn + rr) * K + k0 + lsub, Bsm[p] + (w * 16) * 32);
    };
    stage(0, 0);
    __syncthreads();
    int p = 0;
    int mrow = lane & 15, kg = (lane >> 4) * 8;
    for (int k0 = 0; k0 < K; k0 += 32) {
        if (k0 + 32 < K) stage(k0 + 32, p ^ 1);
        short8 af[2], bfr[2];
#pragma unroll
        for (int i = 0; i < 2; ++i)
            af[i] = *(const short8*)(Asm[p] + (wm * 32 + i * 16 + mrow) * 32 + kg);
#pragma unroll
        for (int j = 0; j < 2; ++j)
            bfr[j] = *(const short8*)(Bsm[p] + (wn * 32 + j * 16 + mrow) * 32 + kg);
#pragma unroll
        for (int i = 0; i < 2; ++i)
#pragma unroll
            for (int j = 0; j < 2; ++j)
                acc[i][j] = __builtin_amdgcn_mfma_f32_16x16x32_bf16(af[i], bfr[j], acc[i][j], 0, 0, 0);
        __syncthreads();
        p ^= 1;
    }
    int ln15 = lane & 15, quad = lane >> 4;
    float* Cfp = Cf ? Cf + (size_t)z * sCf : nullptr;
    short* Cbp = Cb ? Cb + (size_t)z * sCb : nullptr;
#pragma unroll
    for (int i = 0; i < 2; ++i) {
#pragma unroll
        for (int r = 0; r < 4; ++r) {
            int row = bm + wm * 32 + i * 16 + quad * 4 + r;
            long long ro = (long long)row * ldc;
#pragma unroll
            for (int j = 0; j < 2; ++j) {
                int col = bn + wn * 32 + j * 16 + ln15;
                float v = acc[i][j][r];
                if (biasp) v += biasp[col];
                if (addp) v += addp[(long long)row * ldadd + col];
                if (act == 1) v = fmaxf(v, 0.f);
                else if (act == 2) v = 0.5f * v * (1.f + erff(v * 0.70710678118f));
                if (Cfp) Cfp[ro + col] = v;
                if (Cbp) Cbp[ro + col] = f2bf(v);
            }
        }
    }
}

// ---------------- full-row GEMM (N=256) + bias + add + LayerNorm fused epilogue ----------------
// Block: 16 rows x 256 cols, 4 waves (wave w -> cols w*64..+63). grid (M/16, Z).
// xout = gemm + bias + addm (fp32 residual stream); hout = LN(xout)*g+b (bf16).
__global__ __launch_bounds__(256) void gemm_ln_k(
    const short* __restrict__ A, long long sA, int lda,
    const short* __restrict__ Bt, long long sB, int K,
    const float* __restrict__ bias, long long sBias,
    const float* __restrict__ addm, long long sAdd,
    const float* __restrict__ g, const float* __restrict__ b,
    float* __restrict__ xout, long long sX, short* __restrict__ hout, long long sH)
{
    __shared__ short As[2][512];
    __shared__ short Bsm[2][8192];
    __shared__ float redS[16][4], redQ[16][4];
    int z = blockIdx.y;
    int bm = blockIdx.x * 16;
    const short* Ap = A + (size_t)z * sA;
    const short* Bp = Bt + (size_t)z * sB;
    const float* biasp = bias + (size_t)z * sBias;
    const float* addp = addm + (size_t)z * sAdd;
    const float* gp = g + (size_t)z * 256;
    const float* bp = b + (size_t)z * 256;
    float* xo = xout + (size_t)z * sX;
    short* ho = hout + (size_t)z * sH;
    int tid = threadIdx.x;
    int lane = tid & 63, w = tid >> 6;
    int lrow = lane >> 2, lsub = (lane & 3) * 8;
    int mrow = lane & 15, quad = lane >> 4, kg = quad * 8;
    f32x4 acc[4];
#pragma unroll
    for (int j = 0; j < 4; ++j) acc[j] = (f32x4){0.f, 0.f, 0.f, 0.f};

    auto stage = [&](int k0, int p) {
        if (w == 0) GLL(Ap + (size_t)(bm + lrow) * lda + k0 + lsub, As[p]);
#pragma unroll
        for (int s = 0; s < 4; ++s) {
            int r0 = (w * 4 + s) * 16;
            GLL(Bp + (size_t)(r0 + lrow) * K + k0 + lsub, Bsm[p] + r0 * 32);
        }
    };
    stage(0, 0);
    __syncthreads();
    int NK = K >> 5, p = 0;
    for (int kk = 0; kk < NK; ++kk) {
        if (kk + 1 < NK) stage((kk + 1) * 32, p ^ 1);
        short8 af = *(const short8*)(As[p] + mrow * 32 + kg);
#pragma unroll
        for (int j = 0; j < 4; ++j) {
            short8 bfr = *(const short8*)(Bsm[p] + (w * 64 + j * 16 + mrow) * 32 + kg);
            acc[j] = __builtin_amdgcn_mfma_f32_16x16x32_bf16(af, bfr, acc[j], 0, 0, 0);
        }
        __syncthreads();
        p ^= 1;
    }
    // epilogue: v = acc + bias + addm; LN per row
    float v[4][4], s4[4], q4[4];
#pragma unroll
    for (int r = 0; r < 4; ++r) { s4[r] = 0.f; q4[r] = 0.f; }
#pragma unroll
    for (int j = 0; j < 4; ++j) {
        int col = w * 64 + j * 16 + mrow;
        float bb = biasp[col];
#pragma unroll
        for (int r = 0; r < 4; ++r) {
            int row = bm + quad * 4 + r;
            float val = acc[j][r] + bb + addp[(size_t)row * 256 + col];
            v[j][r] = val;
            s4[r] += val;
            q4[r] += val * val;
        }
    }
#pragma unroll
    for (int r = 0; r < 4; ++r) {
#pragma unroll
        for (int msk = 1; msk < 16; msk <<= 1) {
            s4[r] += __shfl_xor(s4[r], msk);
            q4[r] += __shfl_xor(q4[r], msk);
        }
    }
    if (mrow == 0) {
#pragma unroll
        for (int r = 0; r < 4; ++r) {
            redS[quad * 4 + r][w] = s4[r];
            redQ[quad * 4 + r][w] = q4[r];
        }
    }
    __syncthreads();
#pragma unroll
    for (int r = 0; r < 4; ++r) {
        int r16 = quad * 4 + r;
        float S = redS[r16][0] + redS[r16][1] + redS[r16][2] + redS[r16][3];
        float Q = redQ[r16][0] + redQ[r16][1] + redQ[r16][2] + redQ[r16][3];
        float m = S * (1.f / 256.f);
        float var = Q * (1.f / 256.f) - m * m;
        float rs = rsqrtf(var + 1e-5f);
        size_t ro = (size_t)(bm + r16) * 256;
#pragma unroll
        for (int j = 0; j < 4; ++j) {
            int col = w * 64 + j * 16 + mrow;
            xo[ro + col] = v[j][r];
            ho[ro + col] = f2bf((v[j][r] - m) * rs * gp[col] + bp[col]);
        }
    }
}

// ---------------- fused flash attention: per block (64 Q-rows, head, branch) ----------------
__global__ __launch_bounds__(256) void flash_k(const short* __restrict__ qkv, const float* __restrict__ Abias,
                                               short* __restrict__ obuf)
{
    __shared__ short Qs[64 * 72];
    __shared__ short Ks[128 * 72];
    __shared__ short Vt[64 * 136];
    __shared__ short Ps[64 * 136];
    int q0 = blockIdx.x * 64, h = blockIdx.y, br = blockIdx.z;
    const short* qb = qkv + (size_t)br * 1572864;
    int tid = threadIdx.x;
    int lane = tid & 63, w = tid >> 6;
    int ln15 = lane & 15, quad = lane >> 4;
    {
        int row = tid & 63, c0 = (tid >> 6) * 16;
        const short* src = qb + (size_t)(q0 + row) * 1536 + h * 64 + c0;
        *(short8*)(Qs + row * 72 + c0) = *(const short8*)src;
        *(short8*)(Qs + row * 72 + c0 + 8) = *(const short8*)(src + 8);
    }
    f32x4 Oc[4];
    float mrow[4], lsum[4];
#pragma unroll
    for (int i = 0; i < 4; ++i) { Oc[i] = (f32x4){0.f, 0.f, 0.f, 0.f}; mrow[i] = -1e30f; lsum[i] = 0.f; }

    for (int j = 0; j < 8; ++j) {
        int k0 = j * 128;
        {
            int row = tid & 127, half = tid >> 7;
            const short* ks = qb + (size_t)(k0 + row) * 1536 + 512 + h * 64 + half * 32;
#pragma unroll
            for (int g = 0; g < 4; ++g)
                *(short8*)(Ks + row * 72 + half * 32 + g * 8) = *(const short8*)(ks + g * 8);
            const short* vs = qb + (size_t)(k0 + row) * 1536 + 1024 + h * 64 + half * 32;
#pragma unroll
            for (int g = 0; g < 4; ++g) {
                short8 vv = *(const short8*)(vs + g * 8);
#pragma unroll
                for (int e = 0; e < 8; ++e)
                    Vt[(half * 32 + g * 8 + e) * 136 + row] = vv[e];
            }
        }
        __syncthreads();
        short8 aq[2];
#pragma unroll
        for (int g = 0; g < 2; ++g)
            aq[g] = *(const short8*)(Qs + (w * 16 + ln15) * 72 + g * 32 + quad * 8);
        f32x4 Sf[8];
#pragma unroll
        for (int nf = 0; nf < 8; ++nf) Sf[nf] = (f32x4){0.f, 0.f, 0.f, 0.f};
#pragma unroll
        for (int nf = 0; nf < 8; ++nf)
#pragma unroll
            for (int g = 0; g < 2; ++g) {
                short8 bk = *(const short8*)(Ks + (nf * 16 + ln15) * 72 + g * 32 + quad * 8);
                Sf[nf] = __builtin_amdgcn_mfma_f32_16x16x32_bf16(aq[g], bk, Sf[nf], 0, 0, 0);
            }
        float rm[4] = {-1e30f, -1e30f, -1e30f, -1e30f};
#pragma unroll
        for (int nf = 0; nf < 8; ++nf)
#pragma unroll
            for (int r = 0; r < 4; ++r) {
                float v = Sf[nf][r] * 0.125f +
                          Abias[(size_t)(q0 + w * 16 + quad * 4 + r) * 1024 + k0 + nf * 16 + ln15];
                Sf[nf][r] = v;
                rm[r] = fmaxf(rm[r], v);
            }
#pragma unroll
        for (int r = 0; r < 4; ++r)
#pragma unroll
            for (int msk = 1; msk < 16; msk <<= 1)
                rm[r] = fmaxf(rm[r], __shfl_xor(rm[r], msk));
        float alpha[4], rs[4];
#pragma unroll
        for (int r = 0; r < 4; ++r) {
            float mnew = fmaxf(mrow[r], rm[r]);
            alpha[r] = __expf(mrow[r] - mnew);
            mrow[r] = mnew;
            rs[r] = 0.f;
        }
#pragma unroll
        for (int nf = 0; nf < 8; ++nf)
#pragma unroll
            for (int r = 0; r < 4; ++r) {
                float pv = __expf(Sf[nf][r] - mrow[r]);
                Sf[nf][r] = pv;
                rs[r] += pv;
            }
#pragma unroll
        for (int r = 0; r < 4; ++r) {
#pragma unroll
            for (int msk = 1; msk < 16; msk <<= 1)
                rs[r] += __shfl_xor(rs[r], msk);
            lsum[r] = lsum[r] * alpha[r] + rs[r];
        }
#pragma unroll
        for (int nf = 0; nf < 4; ++nf)
#pragma unroll
            for (int r = 0; r < 4; ++r) Oc[nf][r] *= alpha[r];
#pragma unroll
        for (int nf = 0; nf < 8; ++nf)
#pragma unroll
            for (int r = 0; r < 4; ++r)
                Ps[(w * 16 + quad * 4 + r) * 136 + nf * 16 + ln15] = f2bf(Sf[nf][r]);
        __syncthreads();
#pragma unroll
        for (int g = 0; g < 4; ++g) {
            short8 ap = *(const short8*)(Ps + (w * 16 + ln15) * 136 + g * 32 + quad * 8);
#pragma unroll
            for (int nf = 0; nf < 4; ++nf) {
                short8 bv = *(const short8*)(Vt + (nf * 16 + ln15) * 136 + g * 32 + quad * 8);
                Oc[nf] = __builtin_amdgcn_mfma_f32_16x16x32_bf16(ap, bv, Oc[nf], 0, 0, 0);
            }
        }
        __syncthreads();
    }
#pragma unroll
    for (int nf = 0; nf < 4; ++nf)
#pragma unroll
        for (int r = 0; r < 4; ++r) {
            int row = q0 + w * 16 + quad * 4 + r;
            obuf[(size_t)br * 524288 + (size_t)row * 512 + h * 64 + nf * 16 + ln15] =
                f2bf(Oc[nf][r] / lsum[r]);
        }
}

// ---------------- superpixel mean pooling from bf16 HWC (fp32 out; used for LS only) ------------
__global__ __launch_bounds__(256) void pool_bf16_k(const short* __restrict__ in, float* __restrict__ out,
                                                   int C, long long inZ, long long outZ)
{
    int z = blockIdx.y;
    int tid = blockIdx.x * 256 + threadIdx.x;
    int s = tid / C, c = tid - s * C;
    const short* p = in + (size_t)z * inZ + (size_t)s * C + c;
    float acc = 0.f;
#pragma unroll
    for (int j = 0; j < 16; ++j) acc += bf2f(p[(size_t)j * 1024 * C]);
    out[(size_t)z * outZ + (size_t)s * C + c] = acc * (1.f / 16.f);
}

// ---------------- fused pool(conv,256) + concat(b,cb) + relu -> bf16 catr ----------------
__global__ __launch_bounds__(256) void poolcat_k(const short* __restrict__ conv, long long convZ,
                                                 const float* __restrict__ bsrc, long long bZ, int cb,
                                                 short* __restrict__ catr, long long catZ)
{
    int row = blockIdx.x, z = blockIdx.y, tid = threadIdx.x;
    const short* p = conv + (size_t)z * convZ + (size_t)row * 256 + tid;
    float acc = 0.f;
#pragma unroll
    for (int j = 0; j < 16; ++j) acc += bf2f(p[(size_t)j * 262144]);
    int n = 256 + cb;
    short* op = catr + (size_t)z * catZ + (size_t)row * n;
    op[tid] = f2bf(fmaxf(acc * (1.f / 16.f), 0.f));
    if (tid < cb)
        op[256 + tid] = f2bf(fmaxf(bsrc[(size_t)z * bZ + (size_t)row * cb + tid], 0.f));
}

__global__ __launch_bounds__(256) void absdiff_k(const float* __restrict__ a, const float* __restrict__ b,
                                                 float* __restrict__ o, int n)
{
    int i = blockIdx.x * 256 + threadIdx.x;
    if (i < n) o[i] = fabsf(a[i] - b[i]);
}

// ---------------- fp32 head GEMM (64x64 tiles) ----------------
__global__ __launch_bounds__(256) void gemm_f32_head(const float* __restrict__ A, const float* __restrict__ B,
                                                     float* __restrict__ C, int K, int lda, int ldb, int ldc,
                                                     const float* __restrict__ bias, int act)
{
    __shared__ __align__(16) float As[16][68];
    __shared__ __align__(16) float Bs[16][68];
    int bn = blockIdx.x * 64, bm = blockIdx.y * 64;
    int tid = threadIdx.x;
    int tx = tid & 15, ty = tid >> 4;
    float acc[4][4];
#pragma unroll
    for (int r = 0; r < 4; ++r)
#pragma unroll
        for (int c = 0; c < 4; ++c) acc[r][c] = 0.f;
    int mmA = tid >> 2, kqA = (tid & 3) * 4;
    int kkB = tid >> 4, nqB = (tid & 15) * 4;
    for (int k0 = 0; k0 < K; k0 += 16) {
        float4 av = *(const float4*)(A + (long long)(bm + mmA) * lda + k0 + kqA);
        As[kqA + 0][mmA] = av.x; As[kqA + 1][mmA] = av.y;
        As[kqA + 2][mmA] = av.z; As[kqA + 3][mmA] = av.w;
        *(float4*)&Bs[kkB][nqB] = *(const float4*)(B + (long long)(k0 + kkB) * ldb + bn + nqB);
        __syncthreads();
#pragma unroll
        for (int kk = 0; kk < 16; ++kk) {
            float4 a4 = *(const float4*)&As[kk][ty * 4];
            float4 b4 = *(const float4*)&Bs[kk][tx * 4];
            float ar[4] = {a4.x, a4.y, a4.z, a4.w};
            float br[4] = {b4.x, b4.y, b4.z, b4.w};
#pragma unroll
            for (int r = 0; r < 4; ++r)
#pragma unroll
                for (int c = 0; c < 4; ++c) acc[r][c] += ar[r] * br[c];
        }
        __syncthreads();
    }
#pragma unroll
    for (int r = 0; r < 4; ++r) {
        int row = bm + ty * 4 + r;
#pragma unroll
        for (int c = 0; c < 4; ++c) {
            int col = bn + tx * 4 + c;
            float v = acc[r][c] + bias[col];
            if (act == 1) v = fmaxf(v, 0.f);
            C[(long long)row * ldc + col] = v;
        }
    }
}

__global__ __launch_bounds__(256) void head2_k(const float* __restrict__ hh, const float* __restrict__ W2,
                                               const float* __restrict__ b2, float* __restrict__ out)
{
    int s = blockIdx.x * 256 + threadIdx.x;
    if (s >= SPX) return;
    float l0 = b2[0], l1 = b2[1];
    const float* hp = hh + (size_t)s * 128;
    for (int k = 0; k < 128; ++k) {
        float v = hp[k];
        l0 += v * W2[k * 2];
        l1 += v * W2[k * 2 + 1];
    }
    float m = fmaxf(l0, l1);
    float e0 = __expf(l0 - m), e1 = __expf(l1 - m);
    float inv = 1.f / (e0 + e1);
    out[s * 2] = e0 * inv;
    out[s * 2 + 1] = e1 * inv;
}

extern "C" void kernel_launch(void* const* d_in, const int* in_sizes, int n_in,
                              void* d_out, int out_size, void* d_ws, size_t ws_size,
                              hipStream_t stream)
{
    (void)in_sizes; (void)n_in; (void)out_size; (void)ws_size;
    const float* T1 = (const float*)d_in[0];
    const float* T2 = (const float*)d_in[1];
    const float* Abias = (const float*)d_in[3];
    const float* convW_in = (const float*)d_in[4];
    const float* convB_in = (const float*)d_in[5];
    const float* convW = (const float*)d_in[6];
    const float* convB = (const float*)d_in[7];
    const float* fc0_W = (const float*)d_in[8];
    const float* fc0_b = (const float*)d_in[9];
    const float* fc_W = (const float*)d_in[10];
    const float* fc_b = (const float*)d_in[11];
    const float* pos = (const float*)d_in[12];
    const float* ln1_g = (const float*)d_in[13];
    const float* ln1_b = (const float*)d_in[14];
    const float* qkv_W = (const float*)d_in[15];
    const float* out_W = (const float*)d_in[16];
    const float* out_b = (const float*)d_in[17];
    const float* ln2_g = (const float*)d_in[18];
    const float* ln2_b = (const float*)d_in[19];
    const float* ff_W1 = (const float*)d_in[20];
    const float* ff_b1 = (const float*)d_in[21];
    const float* ff_W2 = (const float*)d_in[22];
    const float* ff_b2 = (const float*)d_in[23];
    const float* head_W1 = (const float*)d_in[24];
    const float* head_b1 = (const float*)d_in[25];
    const float* head_W2 = (const float*)d_in[26];
    const float* head_b2 = (const float*)d_in[27];
    float* outp = (float*)d_out;

    char* wp = (char*)d_ws;
    auto alloc = [&](size_t bytes) { char* p = wp; wp += (bytes + 255) & ~(size_t)255; return p; };
    short* cbufA = (short*)alloc(16777216);
    short* cbufB = (short*)alloc(16777216);
    short* wt0   = (short*)alloc(2064384);
    short* wtl   = (short*)alloc(11796480);
    short* zbuf  = (short*)alloc(256);
    short* thwc  = (short*)alloc(14680064);
    short* qkvWT = (short*)alloc(9437184);
    short* outWT = (short*)alloc(3145728);
    short* ff1T  = (short*)alloc(3145728);
    short* ff2T  = (short*)alloc(3145728);
    short* fcT   = (short*)alloc(2621440);
    short* fc0WT = (short*)alloc(245760);
    short* qkvb  = (short*)alloc(6291456);
    short* obuf  = (short*)alloc(2097152);
    short* hbuf  = (short*)alloc(1048576);
    short* h2b   = (short*)alloc(1048576);
    short* ffhb  = (short*)alloc(2097152);
    short* catr  = (short*)alloc(2097152);
    float* LSb    = (float*)alloc(1835008);
    float* xbuf   = (float*)alloc(2097152);
    float* dabs   = (float*)alloc(1048576);
    float* hhb    = (float*)alloc(524288);

    auto gemm = [&](const short* A, long long sA, int lda, const short* Bt, long long sB,
                    int N, int K, float* Cf, long long sCf, short* Cb, long long sCb, int ldc,
                    const float* bias, long long sBias, const float* addm, long long sAdd, int ldadd, int act) {
        gemm64_k<<<dim3((unsigned)(N / 64), 16, 2), 256, 0, stream>>>(
            A, sA, lda, Bt, sB, K, Cf, sCf, Cb, sCb, ldc, bias, sBias, addm, sAdd, ldadd, act);
    };

    // ---- one-time preps (re-run every call; graph-safe) ----
    prep_weights_k<<<27072, 256, 0, stream>>>(convW_in, convW, wt0, wtl, zbuf);
    prep_thwc_k<<<28672, 256, 0, stream>>>(T1, T2, thwc);
    transpose_w_k<<<dim3(48, 8, 12), 256, 0, stream>>>(qkv_W, qkvWT, 256, 1536);
    transpose_w_k<<<dim3(8, 16, 12), 256, 0, stream>>>(out_W, outWT, 512, 256);
    transpose_w_k<<<dim3(16, 8, 12), 256, 0, stream>>>(ff_W1, ff1T, 256, 512);
    transpose_w_k<<<dim3(8, 16, 12), 256, 0, stream>>>(ff_W2, ff2T, 512, 256);
    transpose_w_k<<<dim3(8, 16, 10), 256, 0, stream>>>(fc_W, fcT, 512, 256);
    transpose_w_k<<<dim3(8, 15, 2), 256, 0, stream>>>(fc0_W, fc0WT, 480, 256);

    // LS = pooled raw inputs
    pool_bf16_k<<<dim3(896, 2), 256, 0, stream>>>(thwc, LSb, 224, 3670016LL, 229376LL);
    // conv layer 0 (224 -> 256)
    conv_mfma_k<<<512, 256, 0, stream>>>(thwc, 3670016LL, wt0, 516096LL, convB_in, 256LL,
                                         cbufA, 4194304LL, zbuf, 224);
    short* cur = cbufA; short* nxt = cbufB;
    for (int s = 0; s < 6; ++s) {
        if (s > 0) {
            conv_mfma_k<<<512, 256, 0, stream>>>(cur, 4194304LL, wtl + (size_t)(s - 1) * 2 * 589824,
                                                 589824LL, convB + (size_t)(s - 1) * 512, 256LL,
                                                 nxt, 4194304LL, zbuf, 256);
            short* t = cur; cur = nxt; nxt = t;
        }
        if (s == 0) {
            poolcat_k<<<dim3(1024, 2), 256, 0, stream>>>(cur, 4194304LL, LSb, 229376LL, 224, catr, 491520LL);
            gemm_ln_k<<<dim3(64, 2), 256, 0, stream>>>(
                catr, 491520LL, 480, fc0WT, 122880LL, 480, fc0_b, 256LL,
                pos, 262144LL, ln1_g, ln1_b, xbuf, 262144LL, hbuf, 262144LL);
        } else {
            poolcat_k<<<dim3(1024, 2), 256, 0, stream>>>(cur, 4194304LL, xbuf, 262144LL, 256, catr, 524288LL);
            gemm_ln_k<<<dim3(64, 2), 256, 0, stream>>>(
                catr, 524288LL, 512, fcT + (size_t)(s - 1) * 262144, 131072LL, 512,
                fc_b + (size_t)(s - 1) * 512, 256LL,
                pos + (size_t)s * 524288, 262144LL, ln1_g + s * 512, ln1_b + s * 512,
                xbuf, 262144LL, hbuf, 262144LL);
        }
        gemm(hbuf, 262144, 256, qkvWT + (size_t)s * 786432, 393216, 1536, 256,
             nullptr, 0, qkvb, 1572864, 1536, nullptr, 0, nullptr, 0, 0, 0);
        flash_k<<<dim3(16, 8, 2), 256, 0, stream>>>(qkvb, Abias, obuf);
        gemm_ln_k<<<dim3(64, 2), 256, 0, stream>>>(
            obuf, 524288LL, 512, outWT + (size_t)s * 262144, 131072LL, 512,
            out_b + s * 512, 256LL, xbuf, 262144LL, ln2_g + s * 512, ln2_b + s * 512,
            xbuf, 262144LL, h2b, 262144LL);
        gemm(h2b, 262144, 256, ff1T + (size_t)s * 262144, 131072, 512, 256,
             nullptr, 0, ffhb, 524288, 512, ff_b1 + s * 1024, 512, nullptr, 0, 0, 2);
        gemm(ffhb, 524288, 512, ff2T + (size_t)s * 262144, 131072, 256, 512, xbuf, 262144,
             nullptr, 0, 256, ff_b2 + s * 512, 256, xbuf, 262144, 256, 0);
    }
    // head (fp32)
    absdiff_k<<<1024, 256, 0, stream>>>(xbuf, xbuf + 262144, dabs, 262144);
    gemm_f32_head<<<dim3(2, 16), 256, 0, stream>>>(dabs, head_W1, hhb, 256, 256, 128, 128, head_b1, 1);
    head2_k<<<4, 256, 0, stream>>>(hhb, head_W2, head_b2, outp);
}